// Round 1
// 710.248 us; speedup vs baseline: 1.1104x; 1.1104x over previous
//
#include <hip/hip_runtime.h>
#include <hip/hip_bf16.h>
#include <math.h>

#define S 4096
#define HQ 8
#define NKVH 4
#define D 256
#define HID 2304
#define SW 2048
#define QDIM 2048
#define KVDIM 1024
#define SCALE 0.0625f
#define SOFTCAP 50.0f

typedef __attribute__((ext_vector_type(4))) float f32x4;
typedef __attribute__((ext_vector_type(8))) short short8;   // 8 bf16 = 4 VGPRs (MFMA A/B frag)

__device__ __forceinline__ float bf2f(unsigned v) { return __uint_as_float(v << 16); }
__device__ __forceinline__ unsigned f2bf(float f) {
    unsigned u = __float_as_uint(f);
    return (u + 0x7fffu + ((u >> 16) & 1u)) >> 16;   // round-to-nearest-even
}

__device__ __forceinline__ void store_c(float* p, float v) { *p = v; }
__device__ __forceinline__ void store_c(unsigned short* p, float v) { *p = (unsigned short)f2bf(v); }

// async global->LDS, 16B per lane; lds dst is wave-uniform base (HW adds lane*16)
__device__ __forceinline__ void glls16(const void* g, void* l) {
    __builtin_amdgcn_global_load_lds(
        (const __attribute__((address_space(1))) unsigned int*)g,
        (__attribute__((address_space(3))) unsigned int*)l, 16, 0, 0);
}

// ---------------------------------------------------------------------------
// fp32 -> bf16 elementwise (float4 per thread)
// ---------------------------------------------------------------------------
__global__ __launch_bounds__(256) void cvt_bf16(const float* __restrict__ in,
                                                unsigned short* __restrict__ out)
{
    int i = blockIdx.x * 256 + threadIdx.x;
    float4 v = ((const float4*)in)[i];
    uint2 o;
    o.x = f2bf(v.x) | (f2bf(v.y) << 16);
    o.y = f2bf(v.z) | (f2bf(v.w) << 16);
    ((uint2*)out)[i] = o;
}

// ---------------------------------------------------------------------------
// C[M][N] = A[M][K] @ B[N][K]^T, bf16 in, fp32 accumulate, TC out.
// 128x128 tile, BK=64, 256 threads (2x2 waves, 4x4 MFMA tiles, 2 k-substeps).
// Double-buffered LDS, fragment-major (frag = 16 rows x 32 k = 1 KiB, one
// conflict-free contiguous ds_read_b128 wave read), staged via
// global_load_lds; prefetch k+1 while computing k; ONE barrier per k-step.
// ---------------------------------------------------------------------------
template <typename TC>
__global__ __launch_bounds__(256) void bf16_gemm_bt(const unsigned short* __restrict__ A,
                                                    const unsigned short* __restrict__ B,
                                                    TC* __restrict__ C,
                                                    int M, int N, int K)
{
    __shared__ unsigned short As[2][16 * 512];   // 16 frags x 1 KiB per buffer
    __shared__ unsigned short Bs[2][16 * 512];
    const int t = threadIdx.x;
    const int m0 = blockIdx.y * 128, n0 = blockIdx.x * 128;
    const int w = t >> 6, lid = t & 63, n16 = lid & 15, quad = lid >> 4;
    const int wm = (w >> 1) * 64, wn = (w & 1) * 64;

    f32x4 acc[4][4] = {};

    // stage buffer `buf` with k-panel starting at k0 (8 glls per wave)
    auto stage = [&](int buf, int k0) {
        #pragma unroll
        for (int it = 0; it < 4; ++it) {
            int f  = it * 4 + w;              // wave-uniform frag id 0..15
            int fm = f >> 1, fk = f & 1;
            const size_t goff = (size_t)(fm * 16 + n16) * K + k0 + fk * 32 + quad * 8;
            glls16(A + (size_t)m0 * K + goff, &As[buf][f * 512]);
            glls16(B + (size_t)n0 * K + goff, &Bs[buf][f * 512]);
        }
    };

    const int nk = K / 64;
    stage(0, 0);
    int cur = 0;
    for (int kk = 0; kk < nk; ++kk) {
        asm volatile("s_waitcnt vmcnt(0)" ::: "memory");   // own staging done
        __syncthreads();                                   // everyone's visible
        if (kk + 1 < nk) stage(cur ^ 1, (kk + 1) * 64);    // prefetch next panel
        #pragma unroll
        for (int ks = 0; ks < 2; ++ks) {
            short8 af[4], bfr[4];
            #pragma unroll
            for (int x = 0; x < 4; ++x) {
                af[x]  = *(const short8*)(&As[cur][(((wm >> 4) + x) * 2 + ks) * 512 + lid * 8]);
                bfr[x] = *(const short8*)(&Bs[cur][(((wn >> 4) + x) * 2 + ks) * 512 + lid * 8]);
            }
            #pragma unroll
            for (int i = 0; i < 4; ++i)
                #pragma unroll
                for (int j = 0; j < 4; ++j)
                    acc[i][j] = __builtin_amdgcn_mfma_f32_16x16x32_bf16(af[i], bfr[j], acc[i][j], 0, 0, 0);
        }
        cur ^= 1;
    }

    // C/D layout: col = lane&15, row = quad*4 + reg
    #pragma unroll
    for (int i = 0; i < 4; ++i) {
        #pragma unroll
        for (int j = 0; j < 4; ++j) {
            int rbase = m0 + wm + i * 16 + quad * 4;
            int col   = n0 + wn + j * 16 + n16;
            #pragma unroll
            for (int rg = 0; rg < 4; ++rg)
                store_c(C + (size_t)(rbase + rg) * N + col, acc[i][j][rg]);
        }
    }
}

// ---------------------------------------------------------------------------
// RoPE: read bf16 Q/K (pre-RoPE), write bf16 Qb/Kb (SCALE folded into Q).
// ---------------------------------------------------------------------------
__global__ __launch_bounds__(256) void rope_kernel(const unsigned short* __restrict__ Qf,
                                                   const unsigned short* __restrict__ Kf,
                                                   unsigned short* __restrict__ Qb,
                                                   unsigned short* __restrict__ Kb,
                                                   const int* __restrict__ pos_ids)
{
    int id   = blockIdx.x * 256 + threadIdx.x;   // S * 12 * 128 threads
    int d    = id & 127;
    int rest = id >> 7;
    int hh   = rest % 12;
    int i    = rest / 12;
    float pos = (float)pos_ids[i];
    float inv = __expf((float)d * (-9.210340371976184f / 128.0f));   // 10000^(-d/128)
    float ang = pos * inv;
    float sn, cs;
    sincosf(ang, &sn, &cs);
    if (hh < HQ) {
        const unsigned short* p = Qf + (size_t)i * QDIM + hh * D + d;
        float x0 = bf2f(p[0]), x1 = bf2f(p[128]);
        unsigned short* q = Qb + (size_t)i * QDIM + hh * D + d;
        q[0]   = (unsigned short)f2bf((x0 * cs - x1 * sn) * SCALE);
        q[128] = (unsigned short)f2bf((x1 * cs + x0 * sn) * SCALE);
    } else {
        const unsigned short* p = Kf + (size_t)i * KVDIM + (hh - HQ) * D + d;
        float x0 = bf2f(p[0]), x1 = bf2f(p[128]);
        unsigned short* k = Kb + (size_t)i * KVDIM + (hh - HQ) * D + d;
        k[0]   = (unsigned short)f2bf(x0 * cs - x1 * sn);
        k[128] = (unsigned short)f2bf(x1 * cs + x0 * sn);
    }
}

// ---------------------------------------------------------------------------
// V transpose: Vf [S][KVDIM] bf16 -> Vt [KVDIM][S] bf16.
// ---------------------------------------------------------------------------
__global__ __launch_bounds__(256) void transpose_v(const unsigned short* __restrict__ Vf,
                                                   unsigned short* __restrict__ Vt)
{
    __shared__ float tile[64][65];
    const int s0 = blockIdx.x * 64, d0 = blockIdx.y * 64;
    const int t = threadIdx.x;
    #pragma unroll
    for (int it = 0; it < 4; ++it) {
        int flat = it * 256 + t;
        int r  = flat >> 4;
        int c4 = (flat & 15) * 4;
        uint2 v = *(const uint2*)(Vf + (size_t)(s0 + r) * KVDIM + d0 + c4);
        tile[r][c4 + 0] = bf2f(v.x & 0xffffu); tile[r][c4 + 1] = bf2f(v.x >> 16);
        tile[r][c4 + 2] = bf2f(v.y & 0xffffu); tile[r][c4 + 3] = bf2f(v.y >> 16);
    }
    __syncthreads();
    #pragma unroll
    for (int it = 0; it < 4; ++it) {
        int flat = it * 256 + t;
        int dr  = flat >> 4;
        int sc4 = (flat & 15) * 4;
        uint2 o;
        o.x = f2bf(tile[sc4 + 0][dr]) | (f2bf(tile[sc4 + 1][dr]) << 16);
        o.y = f2bf(tile[sc4 + 2][dr]) | (f2bf(tile[sc4 + 3][dr]) << 16);
        *(uint2*)(Vt + (size_t)(d0 + dr) * S + s0 + sc4) = o;
    }
}

// ---------------------------------------------------------------------------
// MFMA flash attention, occupancy-first restructure.
// Block = 256 threads (4 waves), 64 q-rows (16 per wave), ONE head per block.
// 1D grid of 512 blocks, h = bid&7 (XCD-affine: each XCD mostly serves one
// head's 4 MiB K+V => L2-resident), q-tile = bid>>3.
// KV tiles of 32 keys, K and V double-buffered in LDS, staged via
// global_load_lds with tile j+1 prefetched while computing j.
// LDS = 2*16K (K) + 2*16K (V) + 4K (P) = 68 KiB => TWO independent
// blocks/CU (2 waves/SIMD) so one block's compute hides the other's
// vmcnt drains / barriers / exp chains.
// ---------------------------------------------------------------------------
__global__ __launch_bounds__(256, 2) void attn_kernel(const unsigned short* __restrict__ Qb,
                                                      const unsigned short* __restrict__ Kb,
                                                      const unsigned short* __restrict__ Vt,
                                                      unsigned short* __restrict__ O)
{
    __shared__ unsigned short Ks[2][32 * 256];   // 16 frags: f=nt*8+ks -> K[key=nt*16+n16][k=ks*32+quad*8]
    __shared__ unsigned short Vs[2][256 * 32];   // 16 frags: f=dt      -> Vt[d=dt*16+n16][key=quad*8]
    __shared__ unsigned short Ps[4 * 512];       // per-wave A-frag P[16 rows][32 keys]
    const int t = threadIdx.x;
    const int bid = blockIdx.x;
    const int h = bid & 7, kvh = h >> 1;
    const int i0 = (bid >> 3) * 64;
    const int w = t >> 6, lid = t & 63, n16 = lid & 15, quad = lid >> 4;
    const int qbase = i0 + w * 16;
    unsigned short* Pw = Ps + w * 512;

    auto stage = [&](int buf, int j0) {
        #pragma unroll
        for (int it = 0; it < 4; ++it) {          // K (16 KiB): 16 frags / 4 waves
            int f = it * 4 + w;                   // wave-uniform frag id
            int nt = f >> 3, ks = f & 7;
            glls16(Kb + (size_t)(j0 + nt * 16 + n16) * KVDIM + kvh * D + ks * 32 + quad * 8,
                   &Ks[buf][f * 512]);
        }
        #pragma unroll
        for (int it = 0; it < 4; ++it) {          // V^T (16 KiB): 16 frags / 4 waves
            int f = it * 4 + w;                   // f = dt
            glls16(Vt + (size_t)(kvh * D + f * 16 + n16) * S + j0 + quad * 8,
                   &Vs[buf][f * 512]);
        }
    };

    // Q A-frags in registers: qf[ks], 16 rows per wave
    short8 qf[8];
    #pragma unroll
    for (int ks = 0; ks < 8; ++ks)
        qf[ks] = *(const short8*)(Qb + (size_t)(qbase + n16) * QDIM + h * D + ks * 32 + quad * 8);

    float m_old[4], l[4];
    #pragma unroll
    for (int rg = 0; rg < 4; ++rg) { m_old[rg] = -INFINITY; l[rg] = 0.f; }
    f32x4 Oacc[16] = {};

    const int jt_min = (i0 >= SW) ? ((i0 - (SW - 1)) >> 5) : 0;
    const int jt_max = (i0 + 63) >> 5;

    stage(0, jt_min * 32);
    int cur = 0;

    for (int jt = jt_min; jt <= jt_max; ++jt) {
        const int j0 = jt * 32;
        asm volatile("s_waitcnt vmcnt(0)" ::: "memory");   // own staging (issued last iter) done
        __syncthreads();                                   // all waves' staging visible
        if (jt < jt_max) stage(cur ^ 1, (jt + 1) * 32);    // prefetch next KV tile

        // ---- S = Q K^T (16 MFMA)
        f32x4 sc[2] = {};
        __builtin_amdgcn_s_setprio(1);
        #pragma unroll
        for (int ks = 0; ks < 8; ++ks) {
            #pragma unroll
            for (int nt = 0; nt < 2; ++nt) {
                short8 kf = *(const short8*)(&Ks[cur][(nt * 8 + ks) * 512 + lid * 8]);
                sc[nt] = __builtin_amdgcn_mfma_f32_16x16x32_bf16(qf[ks], kf, sc[nt], 0, 0, 0);
            }
        }
        __builtin_amdgcn_s_setprio(0);

        // ---- softcap + mask (C layout: key = nt*16+n16, q-row = quad*4+rg)
        #pragma unroll
        for (int nt = 0; nt < 2; ++nt) {
            int j = j0 + nt * 16 + n16;
            #pragma unroll
            for (int rg = 0; rg < 4; ++rg) {
                int iq = qbase + quad * 4 + rg;
                float x = sc[nt][rg];
                float e = __expf(x * (2.0f / SOFTCAP));
                x = SOFTCAP * (1.0f - 2.0f / (e + 1.0f));    // 50*tanh(x/50)
                bool ok = (j <= iq) && (iq - j < SW);
                sc[nt][rg] = ok ? x : -1e9f;
            }
        }

        // ---- online softmax per q-row
        float alpha[4];
        #pragma unroll
        for (int rg = 0; rg < 4; ++rg) {
            float mx = fmaxf(sc[0][rg], sc[1][rg]);
            mx = fmaxf(mx, __shfl_xor(mx, 1));
            mx = fmaxf(mx, __shfl_xor(mx, 2));
            mx = fmaxf(mx, __shfl_xor(mx, 4));
            mx = fmaxf(mx, __shfl_xor(mx, 8));
            float mnew = fmaxf(m_old[rg], mx);
            alpha[rg] = __expf(m_old[rg] - mnew);   // -inf -> 0 first tile
            m_old[rg] = mnew;
        }
        // ---- p = exp(s-m), write P to LDS in A-frag order, accumulate l
        #pragma unroll
        for (int rg = 0; rg < 4; ++rg) {
            float rs = 0.f;
            #pragma unroll
            for (int nt = 0; nt < 2; ++nt) {
                float pv = __expf(sc[nt][rg] - m_old[rg]);
                // A-frag: lane' = row + 16*(key>>3), elem = key&7
                Pw[(quad * 4 + rg + 16 * (nt * 2 + (n16 >> 3))) * 8 + (n16 & 7)]
                    = (unsigned short)f2bf(pv);
                rs += pv;
            }
            rs += __shfl_xor(rs, 1); rs += __shfl_xor(rs, 2);
            rs += __shfl_xor(rs, 4); rs += __shfl_xor(rs, 8);
            l[rg] = l[rg] * alpha[rg] + rs;
        }
        #pragma unroll
        for (int dt = 0; dt < 16; ++dt)
            #pragma unroll
            for (int rg = 0; rg < 4; ++rg)
                Oacc[dt][rg] *= alpha[rg];

        asm volatile("s_waitcnt lgkmcnt(0)" ::: "memory");   // P writes visible (wave-private)

        // ---- O += P V (16 MFMA)
        short8 pf = *(const short8*)(Pw + lid * 8);
        __builtin_amdgcn_s_setprio(1);
        #pragma unroll
        for (int dt = 0; dt < 16; ++dt) {
            short8 vf = *(const short8*)(&Vs[cur][dt * 512 + lid * 8]);
            Oacc[dt] = __builtin_amdgcn_mfma_f32_16x16x32_bf16(pf, vf, Oacc[dt], 0, 0, 0);
        }
        __builtin_amdgcn_s_setprio(0);
        cur ^= 1;
    }

    #pragma unroll
    for (int rg = 0; rg < 4; ++rg) l[rg] = 1.0f / l[rg];
    #pragma unroll
    for (int dt = 0; dt < 16; ++dt) {
        int col = h * D + dt * 16 + n16;
        #pragma unroll
        for (int rg = 0; rg < 4; ++rg) {
            int row = qbase + quad * 4 + rg;
            O[(size_t)row * QDIM + col] = (unsigned short)f2bf(Oacc[dt][rg] * l[rg]);
        }
    }
}

extern "C" void kernel_launch(void* const* d_in, const int* in_sizes, int n_in,
                              void* d_out, int out_size, void* d_ws, size_t ws_size,
                              hipStream_t stream) {
    const float* hidden = (const float*)d_in[0];
    // d_in[1] = attention_mask: recomputed analytically, not read
    const float* Wq = (const float*)d_in[2];
    const float* Wk = (const float*)d_in[3];
    const float* Wv = (const float*)d_in[4];
    const float* Wo = (const float*)d_in[5];
    const int* pos = (const int*)d_in[6];
    float* out = (float*)d_out;

    char* ws = (char*)d_ws;
    unsigned short* Qf = (unsigned short*)(ws);                       // [S][2048] bf16, 16 MiB
    unsigned short* Kf = (unsigned short*)(ws + (size_t)(16 << 20));  // [S][1024] bf16,  8 MiB
    unsigned short* Vf = (unsigned short*)(ws + (size_t)(24 << 20));  // [S][1024] bf16,  8 MiB
    unsigned short* Qb = (unsigned short*)(ws + (size_t)(32 << 20));  // 16 MiB
    unsigned short* Kb = (unsigned short*)(ws + (size_t)(48 << 20));  //  8 MiB
    unsigned short* Vt = (unsigned short*)(ws + (size_t)(56 << 20));  //  8 MiB
    unsigned short* Hb = (unsigned short*)(ws + (size_t)(64 << 20));  // [S][2304] bf16, 18 MiB
    unsigned short* Wb = (unsigned short*)(ws + (size_t)(82 << 20));  // weight buf (reused), 9 MiB
    unsigned short* Oa = (unsigned short*)(ws);                       // aliases Qf (dead after rope)

    cvt_bf16<<<(S * HID) / 1024, 256, 0, stream>>>(hidden, Hb);

    cvt_bf16<<<(QDIM * HID) / 1024, 256, 0, stream>>>(Wq, Wb);
    bf16_gemm_bt<unsigned short><<<dim3(QDIM / 128, S / 128), 256, 0, stream>>>(Hb, Wb, Qf, S, QDIM, HID);
    cvt_bf16<<<(KVDIM * HID) / 1024, 256, 0, stream>>>(Wk, Wb);
    bf16_gemm_bt<unsigned short><<<dim3(KVDIM / 128, S / 128), 256, 0, stream>>>(Hb, Wb, Kf, S, KVDIM, HID);
    cvt_bf16<<<(KVDIM * HID) / 1024, 256, 0, stream>>>(Wv, Wb);
    bf16_gemm_bt<unsigned short><<<dim3(KVDIM / 128, S / 128), 256, 0, stream>>>(Hb, Wb, Vf, S, KVDIM, HID);

    rope_kernel<<<(S * 12 * 128) / 256, 256, 0, stream>>>(Qf, Kf, Qb, Kb, pos);
    transpose_v<<<dim3(S / 64, KVDIM / 64), 256, 0, stream>>>(Vf, Vt);

    attn_kernel<<<512, 256, 0, stream>>>(Qb, Kb, Vt, Oa);

    cvt_bf16<<<(HID * QDIM) / 1024, 256, 0, stream>>>(Wo, Wb);
    bf16_gemm_bt<float><<<dim3(HID / 128, S / 128), 256, 0, stream>>>(Oa, Wb, out, S, HID, QDIM);
}

// Round 2
// 656.537 us; speedup vs baseline: 1.2012x; 1.0818x over previous
//
#include <hip/hip_runtime.h>
#include <hip/hip_bf16.h>
#include <math.h>

#define S 4096
#define HQ 8
#define NKVH 4
#define D 256
#define HID 2304
#define SW 2048
#define QDIM 2048
#define KVDIM 1024
#define QKVDIM 4096          // fused Q(2048) | K(1024) | V(1024)
#define SCALE 0.0625f
#define SOFTCAP 50.0f

typedef __attribute__((ext_vector_type(4))) float f32x4;
typedef __attribute__((ext_vector_type(8))) short short8;   // 8 bf16 = 4 VGPRs (MFMA A/B frag)

__device__ __forceinline__ float bf2f(unsigned v) { return __uint_as_float(v << 16); }
__device__ __forceinline__ unsigned f2bf(float f) {
    unsigned u = __float_as_uint(f);
    return (u + 0x7fffu + ((u >> 16) & 1u)) >> 16;   // round-to-nearest-even
}

__device__ __forceinline__ void store_c(float* p, float v) { *p = v; }
__device__ __forceinline__ void store_c(unsigned short* p, float v) { *p = (unsigned short)f2bf(v); }

// async global->LDS, 16B per lane; lds dst is wave-uniform base (HW adds lane*16)
__device__ __forceinline__ void glls16(const void* g, void* l) {
    __builtin_amdgcn_global_load_lds(
        (const __attribute__((address_space(1))) unsigned int*)g,
        (__attribute__((address_space(3))) unsigned int*)l, 16, 0, 0);
}

// ---------------------------------------------------------------------------
// fp32 -> bf16 elementwise (float4 per thread)
// ---------------------------------------------------------------------------
__global__ __launch_bounds__(256) void cvt_bf16(const float* __restrict__ in,
                                                unsigned short* __restrict__ out)
{
    int i = blockIdx.x * 256 + threadIdx.x;
    float4 v = ((const float4*)in)[i];
    uint2 o;
    o.x = f2bf(v.x) | (f2bf(v.y) << 16);
    o.y = f2bf(v.z) | (f2bf(v.w) << 16);
    ((uint2*)out)[i] = o;
}

// ---------------------------------------------------------------------------
// C[M][N] = A[M][K] @ B[N][K]^T, bf16 in, fp32 accumulate, TC out.
// 128x128 tile, BK=64, 256 threads (2x2 waves, 4x4 MFMA tiles, 2 k-substeps).
// Double-buffered LDS, fragment-major (frag = 16 rows x 32 k = 1 KiB, one
// conflict-free contiguous ds_read_b128 wave read), staged via
// global_load_lds; prefetch k+1 while computing k; ONE barrier per k-step.
// XCD-chunk swizzle (bijective, m204): each XCD works a contiguous range of
// flattened tile ids -> shared A-panels stay in its private L2.
// ---------------------------------------------------------------------------
template <typename TC>
__global__ __launch_bounds__(256) void bf16_gemm_bt(const unsigned short* __restrict__ A,
                                                    const unsigned short* __restrict__ B,
                                                    TC* __restrict__ C,
                                                    int M, int N, int K)
{
    __shared__ unsigned short As[2][16 * 512];   // 16 frags x 1 KiB per buffer
    __shared__ unsigned short Bs[2][16 * 512];
    const int t = threadIdx.x;

    // bijective XCD swizzle of the flattened tile id
    const int nbx = gridDim.x;
    const int nwg = nbx * gridDim.y;
    {
    }
    int flat = blockIdx.y * nbx + blockIdx.x;
    const int q8 = nwg >> 3, r8 = nwg & 7;
    const int xcd = flat & 7, orig = flat >> 3;
    const int wg = (xcd < r8 ? xcd * (q8 + 1) : r8 * (q8 + 1) + (xcd - r8) * q8) + orig;
    const int m0 = (wg / nbx) * 128, n0 = (wg % nbx) * 128;

    const int w = t >> 6, lid = t & 63, n16 = lid & 15, quad = lid >> 4;
    const int wm = (w >> 1) * 64, wn = (w & 1) * 64;

    f32x4 acc[4][4] = {};

    // stage buffer `buf` with k-panel starting at k0 (8 glls per wave)
    auto stage = [&](int buf, int k0) {
        #pragma unroll
        for (int it = 0; it < 4; ++it) {
            int f  = it * 4 + w;              // wave-uniform frag id 0..15
            int fm = f >> 1, fk = f & 1;
            const size_t goff = (size_t)(fm * 16 + n16) * K + k0 + fk * 32 + quad * 8;
            glls16(A + (size_t)m0 * K + goff, &As[buf][f * 512]);
            glls16(B + (size_t)n0 * K + goff, &Bs[buf][f * 512]);
        }
    };

    const int nk = K / 64;
    stage(0, 0);
    int cur = 0;
    for (int kk = 0; kk < nk; ++kk) {
        asm volatile("s_waitcnt vmcnt(0)" ::: "memory");   // own staging done
        __syncthreads();                                   // everyone's visible
        if (kk + 1 < nk) stage(cur ^ 1, (kk + 1) * 64);    // prefetch next panel
        #pragma unroll
        for (int ks = 0; ks < 2; ++ks) {
            short8 af[4], bfr[4];
            #pragma unroll
            for (int x = 0; x < 4; ++x) {
                af[x]  = *(const short8*)(&As[cur][(((wm >> 4) + x) * 2 + ks) * 512 + lid * 8]);
                bfr[x] = *(const short8*)(&Bs[cur][(((wn >> 4) + x) * 2 + ks) * 512 + lid * 8]);
            }
            __builtin_amdgcn_s_setprio(1);
            #pragma unroll
            for (int i = 0; i < 4; ++i)
                #pragma unroll
                for (int j = 0; j < 4; ++j)
                    acc[i][j] = __builtin_amdgcn_mfma_f32_16x16x32_bf16(af[i], bfr[j], acc[i][j], 0, 0, 0);
            __builtin_amdgcn_s_setprio(0);
        }
        cur ^= 1;
    }

    // C/D layout: col = lane&15, row = quad*4 + reg
    #pragma unroll
    for (int i = 0; i < 4; ++i) {
        #pragma unroll
        for (int j = 0; j < 4; ++j) {
            int rbase = m0 + wm + i * 16 + quad * 4;
            int col   = n0 + wn + j * 16 + n16;
            #pragma unroll
            for (int rg = 0; rg < 4; ++rg)
                store_c(C + (size_t)(rbase + rg) * N + col, acc[i][j][rg]);
        }
    }
}

// ---------------------------------------------------------------------------
// RoPE: read bf16 Q/K from fused QKV [S][4096] (Q cols 0..2047, K cols
// 2048..3071), write bf16 Qb [S][2048] / Kb [S][1024] (SCALE folded into Q).
// ---------------------------------------------------------------------------
__global__ __launch_bounds__(256) void rope_kernel(const unsigned short* __restrict__ QKV,
                                                   unsigned short* __restrict__ Qb,
                                                   unsigned short* __restrict__ Kb,
                                                   const int* __restrict__ pos_ids)
{
    int id   = blockIdx.x * 256 + threadIdx.x;   // S * 12 * 128 threads
    int d    = id & 127;
    int rest = id >> 7;
    int hh   = rest % 12;
    int i    = rest / 12;
    float pos = (float)pos_ids[i];
    float inv = __expf((float)d * (-9.210340371976184f / 128.0f));   // 10000^(-d/128)
    float ang = pos * inv;
    float sn, cs;
    sincosf(ang, &sn, &cs);
    if (hh < HQ) {
        const unsigned short* p = QKV + (size_t)i * QKVDIM + hh * D + d;
        float x0 = bf2f(p[0]), x1 = bf2f(p[128]);
        unsigned short* q = Qb + (size_t)i * QDIM + hh * D + d;
        q[0]   = (unsigned short)f2bf((x0 * cs - x1 * sn) * SCALE);
        q[128] = (unsigned short)f2bf((x1 * cs + x0 * sn) * SCALE);
    } else {
        const unsigned short* p = QKV + (size_t)i * QKVDIM + QDIM + (hh - HQ) * D + d;
        float x0 = bf2f(p[0]), x1 = bf2f(p[128]);
        unsigned short* k = Kb + (size_t)i * KVDIM + (hh - HQ) * D + d;
        k[0]   = (unsigned short)f2bf(x0 * cs - x1 * sn);
        k[128] = (unsigned short)f2bf(x1 * cs + x0 * sn);
    }
}

// ---------------------------------------------------------------------------
// V transpose: fused QKV [S][4096] cols 3072..4095 -> Vt [KVDIM][S] bf16.
// ---------------------------------------------------------------------------
__global__ __launch_bounds__(256) void transpose_v(const unsigned short* __restrict__ QKV,
                                                   unsigned short* __restrict__ Vt)
{
    __shared__ float tile[64][65];
    const int s0 = blockIdx.x * 64, d0 = blockIdx.y * 64;
    const int t = threadIdx.x;
    #pragma unroll
    for (int it = 0; it < 4; ++it) {
        int flat = it * 256 + t;
        int r  = flat >> 4;
        int c4 = (flat & 15) * 4;
        uint2 v = *(const uint2*)(QKV + (size_t)(s0 + r) * QKVDIM + (QDIM + KVDIM) + d0 + c4);
        tile[r][c4 + 0] = bf2f(v.x & 0xffffu); tile[r][c4 + 1] = bf2f(v.x >> 16);
        tile[r][c4 + 2] = bf2f(v.y & 0xffffu); tile[r][c4 + 3] = bf2f(v.y >> 16);
    }
    __syncthreads();
    #pragma unroll
    for (int it = 0; it < 4; ++it) {
        int flat = it * 256 + t;
        int dr  = flat >> 4;
        int sc4 = (flat & 15) * 4;
        uint2 o;
        o.x = f2bf(tile[sc4 + 0][dr]) | (f2bf(tile[sc4 + 1][dr]) << 16);
        o.y = f2bf(tile[sc4 + 2][dr]) | (f2bf(tile[sc4 + 3][dr]) << 16);
        *(uint2*)(Vt + (size_t)(d0 + dr) * S + s0 + sc4) = o;
    }
}

// ---------------------------------------------------------------------------
// MFMA flash attention. Block = 256 threads (4 waves), 64 q-rows (16/wave),
// ONE head per block. 1D grid of 512 blocks, h = bid&7 (XCD-affine: each XCD
// mostly serves one head's K+V => L2-resident), q-tile = bid>>3.
// KV tiles of 32 keys, K and V double-buffered in LDS via global_load_lds,
// tile j+1 prefetched while computing j. LDS = 68 KiB => 2 blocks/CU.
// ---------------------------------------------------------------------------
__global__ __launch_bounds__(256, 2) void attn_kernel(const unsigned short* __restrict__ Qb,
                                                      const unsigned short* __restrict__ Kb,
                                                      const unsigned short* __restrict__ Vt,
                                                      unsigned short* __restrict__ O)
{
    __shared__ unsigned short Ks[2][32 * 256];   // 16 frags: f=nt*8+ks -> K[key=nt*16+n16][k=ks*32+quad*8]
    __shared__ unsigned short Vs[2][256 * 32];   // 16 frags: f=dt      -> Vt[d=dt*16+n16][key=quad*8]
    __shared__ unsigned short Ps[4 * 512];       // per-wave A-frag P[16 rows][32 keys]
    const int t = threadIdx.x;
    const int bid = blockIdx.x;
    const int h = bid & 7, kvh = h >> 1;
    const int i0 = (bid >> 3) * 64;
    const int w = t >> 6, lid = t & 63, n16 = lid & 15, quad = lid >> 4;
    const int qbase = i0 + w * 16;
    unsigned short* Pw = Ps + w * 512;

    auto stage = [&](int buf, int j0) {
        #pragma unroll
        for (int it = 0; it < 4; ++it) {          // K (16 KiB): 16 frags / 4 waves
            int f = it * 4 + w;                   // wave-uniform frag id
            int nt = f >> 3, ks = f & 7;
            glls16(Kb + (size_t)(j0 + nt * 16 + n16) * KVDIM + kvh * D + ks * 32 + quad * 8,
                   &Ks[buf][f * 512]);
        }
        #pragma unroll
        for (int it = 0; it < 4; ++it) {          // V^T (16 KiB): 16 frags / 4 waves
            int f = it * 4 + w;                   // f = dt
            glls16(Vt + (size_t)(kvh * D + f * 16 + n16) * S + j0 + quad * 8,
                   &Vs[buf][f * 512]);
        }
    };

    // Q A-frags in registers: qf[ks], 16 rows per wave
    short8 qf[8];
    #pragma unroll
    for (int ks = 0; ks < 8; ++ks)
        qf[ks] = *(const short8*)(Qb + (size_t)(qbase + n16) * QDIM + h * D + ks * 32 + quad * 8);

    float m_old[4], l[4];
    #pragma unroll
    for (int rg = 0; rg < 4; ++rg) { m_old[rg] = -INFINITY; l[rg] = 0.f; }
    f32x4 Oacc[16] = {};

    const int jt_min = (i0 >= SW) ? ((i0 - (SW - 1)) >> 5) : 0;
    const int jt_max = (i0 + 63) >> 5;

    stage(0, jt_min * 32);
    int cur = 0;

    for (int jt = jt_min; jt <= jt_max; ++jt) {
        const int j0 = jt * 32;
        asm volatile("s_waitcnt vmcnt(0)" ::: "memory");   // own staging (issued last iter) done
        __syncthreads();                                   // all waves' staging visible
        if (jt < jt_max) stage(cur ^ 1, (jt + 1) * 32);    // prefetch next KV tile

        // ---- S = Q K^T (16 MFMA)
        f32x4 sc[2] = {};
        __builtin_amdgcn_s_setprio(1);
        #pragma unroll
        for (int ks = 0; ks < 8; ++ks) {
            #pragma unroll
            for (int nt = 0; nt < 2; ++nt) {
                short8 kf = *(const short8*)(&Ks[cur][(nt * 8 + ks) * 512 + lid * 8]);
                sc[nt] = __builtin_amdgcn_mfma_f32_16x16x32_bf16(qf[ks], kf, sc[nt], 0, 0, 0);
            }
        }
        __builtin_amdgcn_s_setprio(0);

        // ---- softcap + mask (C layout: key = nt*16+n16, q-row = quad*4+rg)
        #pragma unroll
        for (int nt = 0; nt < 2; ++nt) {
            int j = j0 + nt * 16 + n16;
            #pragma unroll
            for (int rg = 0; rg < 4; ++rg) {
                int iq = qbase + quad * 4 + rg;
                float x = sc[nt][rg];
                float e = __expf(x * (2.0f / SOFTCAP));
                x = SOFTCAP * (1.0f - 2.0f / (e + 1.0f));    // 50*tanh(x/50)
                bool ok = (j <= iq) && (iq - j < SW);
                sc[nt][rg] = ok ? x : -1e9f;
            }
        }

        // ---- online softmax per q-row
        float alpha[4];
        #pragma unroll
        for (int rg = 0; rg < 4; ++rg) {
            float mx = fmaxf(sc[0][rg], sc[1][rg]);
            mx = fmaxf(mx, __shfl_xor(mx, 1));
            mx = fmaxf(mx, __shfl_xor(mx, 2));
            mx = fmaxf(mx, __shfl_xor(mx, 4));
            mx = fmaxf(mx, __shfl_xor(mx, 8));
            float mnew = fmaxf(m_old[rg], mx);
            alpha[rg] = __expf(m_old[rg] - mnew);   // -inf -> 0 first tile
            m_old[rg] = mnew;
        }
        // ---- p = exp(s-m), write P to LDS in A-frag order, accumulate l
        #pragma unroll
        for (int rg = 0; rg < 4; ++rg) {
            float rs = 0.f;
            #pragma unroll
            for (int nt = 0; nt < 2; ++nt) {
                float pv = __expf(sc[nt][rg] - m_old[rg]);
                // A-frag: lane' = row + 16*(key>>3), elem = key&7
                Pw[(quad * 4 + rg + 16 * (nt * 2 + (n16 >> 3))) * 8 + (n16 & 7)]
                    = (unsigned short)f2bf(pv);
                rs += pv;
            }
            rs += __shfl_xor(rs, 1); rs += __shfl_xor(rs, 2);
            rs += __shfl_xor(rs, 4); rs += __shfl_xor(rs, 8);
            l[rg] = l[rg] * alpha[rg] + rs;
        }
        #pragma unroll
        for (int dt = 0; dt < 16; ++dt)
            #pragma unroll
            for (int rg = 0; rg < 4; ++rg)
                Oacc[dt][rg] *= alpha[rg];

        asm volatile("s_waitcnt lgkmcnt(0)" ::: "memory");   // P writes visible (wave-private)

        // ---- O += P V (16 MFMA)
        short8 pf = *(const short8*)(Pw + lid * 8);
        __builtin_amdgcn_s_setprio(1);
        #pragma unroll
        for (int dt = 0; dt < 16; ++dt) {
            short8 vf = *(const short8*)(&Vs[cur][dt * 512 + lid * 8]);
            Oacc[dt] = __builtin_amdgcn_mfma_f32_16x16x32_bf16(pf, vf, Oacc[dt], 0, 0, 0);
        }
        __builtin_amdgcn_s_setprio(0);
        cur ^= 1;
    }

    #pragma unroll
    for (int rg = 0; rg < 4; ++rg) l[rg] = 1.0f / l[rg];
    #pragma unroll
    for (int dt = 0; dt < 16; ++dt) {
        int col = h * D + dt * 16 + n16;
        #pragma unroll
        for (int rg = 0; rg < 4; ++rg) {
            int row = qbase + quad * 4 + rg;
            O[(size_t)row * QDIM + col] = (unsigned short)f2bf(Oacc[dt][rg] * l[rg]);
        }
    }
}

extern "C" void kernel_launch(void* const* d_in, const int* in_sizes, int n_in,
                              void* d_out, int out_size, void* d_ws, size_t ws_size,
                              hipStream_t stream) {
    const float* hidden = (const float*)d_in[0];
    // d_in[1] = attention_mask: recomputed analytically, not read
    const float* Wq = (const float*)d_in[2];
    const float* Wk = (const float*)d_in[3];
    const float* Wv = (const float*)d_in[4];
    const float* Wo = (const float*)d_in[5];
    const int* pos = (const int*)d_in[6];
    float* out = (float*)d_out;

    // workspace layout (85 MiB total, aggressive aliasing):
    //  [0,18M)   Hb  [S][2304] bf16            -> dead after QKV GEMM; Qb [S][2048] (16M) aliases
    //  [18,37M)  Wqkv [4096][2304] bf16 (19M)  -> dead after QKV GEMM; Wo bf16 (9M) aliases
    //  [37,69M)  QKVf [S][4096] bf16 (32M)     -> dead after rope+transpose; Oa (16M) aliases
    //  [69,77M)  Kb  [S][1024] bf16 (8M)
    //  [77,85M)  Vt  [1024][S] bf16 (8M)
    char* ws = (char*)d_ws;
    unsigned short* Hb   = (unsigned short*)(ws);
    unsigned short* Qb   = (unsigned short*)(ws);
    unsigned short* Wqkv = (unsigned short*)(ws + (size_t)(18 << 20));
    unsigned short* QKVf = (unsigned short*)(ws + (size_t)(37 << 20));
    unsigned short* Oa   = (unsigned short*)(ws + (size_t)(37 << 20));
    unsigned short* Kb   = (unsigned short*)(ws + (size_t)(69 << 20));
    unsigned short* Vt   = (unsigned short*)(ws + (size_t)(77 << 20));

    cvt_bf16<<<(S * HID) / 1024, 256, 0, stream>>>(hidden, Hb);
    cvt_bf16<<<(QDIM * HID) / 1024, 256, 0, stream>>>(Wq, Wqkv);
    cvt_bf16<<<(KVDIM * HID) / 1024, 256, 0, stream>>>(Wk, Wqkv + (size_t)QDIM * HID);
    cvt_bf16<<<(KVDIM * HID) / 1024, 256, 0, stream>>>(Wv, Wqkv + (size_t)(QDIM + KVDIM) * HID);

    // fused QKV projection: [4096][2304] @ [4096][2304]^T -> [4096][4096]
    bf16_gemm_bt<unsigned short><<<dim3(QKVDIM / 128, S / 128), 256, 0, stream>>>(
        Hb, Wqkv, QKVf, S, QKVDIM, HID);

    rope_kernel<<<(S * 12 * 128) / 256, 256, 0, stream>>>(QKVf, Qb, Kb, pos);
    transpose_v<<<dim3(S / 64, KVDIM / 64), 256, 0, stream>>>(QKVf, Vt);

    attn_kernel<<<512, 256, 0, stream>>>(Qb, Kb, Vt, Oa);

    cvt_bf16<<<(HID * QDIM) / 1024, 256, 0, stream>>>(Wo, Wqkv);
    bf16_gemm_bt<float><<<dim3(HID / 128, S / 128), 256, 0, stream>>>(Oa, Wqkv, out, S, HID, QDIM);
}

// Round 3
// 646.945 us; speedup vs baseline: 1.2190x; 1.0148x over previous
//
#include <hip/hip_runtime.h>
#include <hip/hip_bf16.h>
#include <math.h>

#define S 4096
#define HQ 8
#define NKVH 4
#define D 256
#define HID 2304
#define SW 2048
#define QDIM 2048
#define KVDIM 1024
#define QKVDIM 4096          // fused Q(2048) | K(1024) | V(1024)
#define SCALE 0.0625f
#define SOFTCAP 50.0f

typedef __attribute__((ext_vector_type(4))) float f32x4;
typedef __attribute__((ext_vector_type(8))) short short8;   // 8 bf16 = 4 VGPRs (MFMA A/B frag)

__device__ __forceinline__ float bf2f(unsigned v) { return __uint_as_float(v << 16); }
__device__ __forceinline__ unsigned f2bf(float f) {
    unsigned u = __float_as_uint(f);
    return (u + 0x7fffu + ((u >> 16) & 1u)) >> 16;   // round-to-nearest-even
}

__device__ __forceinline__ void store_c(float* p, float v) { *p = v; }
__device__ __forceinline__ void store_c(unsigned short* p, float v) { *p = (unsigned short)f2bf(v); }

// async global->LDS, 16B per lane; lds dst is wave-uniform base (HW adds lane*16)
__device__ __forceinline__ void glls16(const void* g, void* l) {
    __builtin_amdgcn_global_load_lds(
        (const __attribute__((address_space(1))) unsigned int*)g,
        (__attribute__((address_space(3))) unsigned int*)l, 16, 0, 0);
}

// ---------------------------------------------------------------------------
// fp32 -> bf16 elementwise (float4 per thread)
// ---------------------------------------------------------------------------
__global__ __launch_bounds__(256) void cvt_bf16(const float* __restrict__ in,
                                                unsigned short* __restrict__ out)
{
    int i = blockIdx.x * 256 + threadIdx.x;
    float4 v = ((const float4*)in)[i];
    uint2 o;
    o.x = f2bf(v.x) | (f2bf(v.y) << 16);
    o.y = f2bf(v.z) | (f2bf(v.w) << 16);
    ((uint2*)out)[i] = o;
}

// ---------------------------------------------------------------------------
// C[M][N] = A[M][K] @ B[N][K]^T, bf16 in, fp32 accumulate, TC out.
// 128x128 tile, BK=64, 256 threads (2x2 waves, 4x4 MFMA tiles, 2 k-substeps).
// Double-buffered LDS, fragment-major, staged via global_load_lds;
// prefetch k+1 while computing k; ONE barrier per k-step.
// Rasterization: bijective XCD chunking (contiguous wg range per XCD), then
// grouped raster inside (8 m-tiles per band, n sweeps within band) so an
// XCD's concurrent blocks share both A- and B-panels in its private L2.
// Requires gridDim.y % 8 == 0 and nwg % 8 == 0.
// ---------------------------------------------------------------------------
template <typename TC>
__global__ __launch_bounds__(256) void bf16_gemm_bt(const unsigned short* __restrict__ A,
                                                    const unsigned short* __restrict__ B,
                                                    TC* __restrict__ C,
                                                    int M, int N, int K)
{
    __shared__ unsigned short As[2][16 * 512];   // 16 frags x 1 KiB per buffer
    __shared__ unsigned short Bs[2][16 * 512];
    const int t = threadIdx.x;

    // bijective XCD swizzle of the flattened tile id
    const int nbx = gridDim.x;
    const int nwg = nbx * gridDim.y;
    int flat = blockIdx.y * nbx + blockIdx.x;
    const int q8 = nwg >> 3, r8 = nwg & 7;
    const int xcd = flat & 7, orig = flat >> 3;
    const int wg = (xcd < r8 ? xcd * (q8 + 1) : r8 * (q8 + 1) + (xcd - r8) * q8) + orig;
    // grouped raster: bands of 8 m-tiles, n sweeps within a band
    const int band = wg / (8 * nbx);
    const int rem  = wg - band * 8 * nbx;
    const int m0 = (band * 8 + (rem & 7)) * 128;
    const int n0 = (rem >> 3) * 128;

    const int w = t >> 6, lid = t & 63, n16 = lid & 15, quad = lid >> 4;
    const int wm = (w >> 1) * 64, wn = (w & 1) * 64;

    f32x4 acc[4][4] = {};

    // stage buffer `buf` with k-panel starting at k0 (8 glls per wave)
    auto stage = [&](int buf, int k0) {
        #pragma unroll
        for (int it = 0; it < 4; ++it) {
            int f  = it * 4 + w;              // wave-uniform frag id 0..15
            int fm = f >> 1, fk = f & 1;
            const size_t goff = (size_t)(fm * 16 + n16) * K + k0 + fk * 32 + quad * 8;
            glls16(A + (size_t)m0 * K + goff, &As[buf][f * 512]);
            glls16(B + (size_t)n0 * K + goff, &Bs[buf][f * 512]);
        }
    };

    const int nk = K / 64;
    stage(0, 0);
    int cur = 0;
    for (int kk = 0; kk < nk; ++kk) {
        asm volatile("s_waitcnt vmcnt(0)" ::: "memory");   // own staging done
        __syncthreads();                                   // everyone's visible
        if (kk + 1 < nk) stage(cur ^ 1, (kk + 1) * 64);    // prefetch next panel
        #pragma unroll
        for (int ks = 0; ks < 2; ++ks) {
            short8 af[4], bfr[4];
            #pragma unroll
            for (int x = 0; x < 4; ++x) {
                af[x]  = *(const short8*)(&As[cur][(((wm >> 4) + x) * 2 + ks) * 512 + lid * 8]);
                bfr[x] = *(const short8*)(&Bs[cur][(((wn >> 4) + x) * 2 + ks) * 512 + lid * 8]);
            }
            __builtin_amdgcn_s_setprio(1);
            #pragma unroll
            for (int i = 0; i < 4; ++i)
                #pragma unroll
                for (int j = 0; j < 4; ++j)
                    acc[i][j] = __builtin_amdgcn_mfma_f32_16x16x32_bf16(af[i], bfr[j], acc[i][j], 0, 0, 0);
            __builtin_amdgcn_s_setprio(0);
        }
        cur ^= 1;
    }

    // C/D layout: col = lane&15, row = quad*4 + reg
    #pragma unroll
    for (int i = 0; i < 4; ++i) {
        #pragma unroll
        for (int j = 0; j < 4; ++j) {
            int rbase = m0 + wm + i * 16 + quad * 4;
            int col   = n0 + wn + j * 16 + n16;
            #pragma unroll
            for (int rg = 0; rg < 4; ++rg)
                store_c(C + (size_t)(rbase + rg) * N + col, acc[i][j][rg]);
        }
    }
}

// ---------------------------------------------------------------------------
// RoPE: read bf16 Q/K from fused QKV [S][4096] (Q cols 0..2047, K cols
// 2048..3071), write bf16 Qb [S][2048] / Kb [S][1024] (SCALE folded into Q).
// ---------------------------------------------------------------------------
__global__ __launch_bounds__(256) void rope_kernel(const unsigned short* __restrict__ QKV,
                                                   unsigned short* __restrict__ Qb,
                                                   unsigned short* __restrict__ Kb,
                                                   const int* __restrict__ pos_ids)
{
    int id   = blockIdx.x * 256 + threadIdx.x;   // S * 12 * 128 threads
    int d    = id & 127;
    int rest = id >> 7;
    int hh   = rest % 12;
    int i    = rest / 12;
    float pos = (float)pos_ids[i];
    float inv = __expf((float)d * (-9.210340371976184f / 128.0f));   // 10000^(-d/128)
    float ang = pos * inv;
    float sn, cs;
    sincosf(ang, &sn, &cs);
    if (hh < HQ) {
        const unsigned short* p = QKV + (size_t)i * QKVDIM + hh * D + d;
        float x0 = bf2f(p[0]), x1 = bf2f(p[128]);
        unsigned short* q = Qb + (size_t)i * QDIM + hh * D + d;
        q[0]   = (unsigned short)f2bf((x0 * cs - x1 * sn) * SCALE);
        q[128] = (unsigned short)f2bf((x1 * cs + x0 * sn) * SCALE);
    } else {
        const unsigned short* p = QKV + (size_t)i * QKVDIM + QDIM + (hh - HQ) * D + d;
        float x0 = bf2f(p[0]), x1 = bf2f(p[128]);
        unsigned short* k = Kb + (size_t)i * KVDIM + (hh - HQ) * D + d;
        k[0]   = (unsigned short)f2bf(x0 * cs - x1 * sn);
        k[128] = (unsigned short)f2bf(x1 * cs + x0 * sn);
    }
}

// ---------------------------------------------------------------------------
// V transpose: fused QKV [S][4096] cols 3072..4095 -> Vt [KVDIM][S] bf16.
// ---------------------------------------------------------------------------
__global__ __launch_bounds__(256) void transpose_v(const unsigned short* __restrict__ QKV,
                                                   unsigned short* __restrict__ Vt)
{
    __shared__ float tile[64][65];
    const int s0 = blockIdx.x * 64, d0 = blockIdx.y * 64;
    const int t = threadIdx.x;
    #pragma unroll
    for (int it = 0; it < 4; ++it) {
        int flat = it * 256 + t;
        int r  = flat >> 4;
        int c4 = (flat & 15) * 4;
        uint2 v = *(const uint2*)(QKV + (size_t)(s0 + r) * QKVDIM + (QDIM + KVDIM) + d0 + c4);
        tile[r][c4 + 0] = bf2f(v.x & 0xffffu); tile[r][c4 + 1] = bf2f(v.x >> 16);
        tile[r][c4 + 2] = bf2f(v.y & 0xffffu); tile[r][c4 + 3] = bf2f(v.y >> 16);
    }
    __syncthreads();
    #pragma unroll
    for (int it = 0; it < 4; ++it) {
        int flat = it * 256 + t;
        int dr  = flat >> 4;
        int sc4 = (flat & 15) * 4;
        uint2 o;
        o.x = f2bf(tile[sc4 + 0][dr]) | (f2bf(tile[sc4 + 1][dr]) << 16);
        o.y = f2bf(tile[sc4 + 2][dr]) | (f2bf(tile[sc4 + 3][dr]) << 16);
        *(uint2*)(Vt + (size_t)(d0 + dr) * S + s0 + sc4) = o;
    }
}

// ---------------------------------------------------------------------------
// MFMA flash attention. Block = 256 threads (4 waves), 64 q-rows (16/wave),
// ONE head per block. Grid 512, 2 blocks/CU => whole grid co-resident.
// Work per q-tile g is ~2g+2 tiles (g<32) / ~66 (g>=32) due to the sliding
// window. Load-balance remap: bid<256 -> g=u, bid>=256 -> g=63-u
// (u=(bid&255)>>3), so the natural (c, c+256) same-CU pairing gives every CU
// a complementary pair (~69 tile-units, vs 68..130 before). h = bid&7 is
// preserved (same head on both pair members, XCD-affine KV in L2).
// KV tiles of 32 keys, K/V double-buffered via global_load_lds, tile j+1
// prefetched while computing j. LDS = 68 KiB => 2 blocks/CU.
// ---------------------------------------------------------------------------
__global__ __launch_bounds__(256, 2) void attn_kernel(const unsigned short* __restrict__ Qb,
                                                      const unsigned short* __restrict__ Kb,
                                                      const unsigned short* __restrict__ Vt,
                                                      unsigned short* __restrict__ O)
{
    __shared__ unsigned short Ks[2][32 * 256];   // 16 frags: f=nt*8+ks -> K[key=nt*16+n16][k=ks*32+quad*8]
    __shared__ unsigned short Vs[2][256 * 32];   // 16 frags: f=dt      -> Vt[d=dt*16+n16][key=quad*8]
    __shared__ unsigned short Ps[4 * 512];       // per-wave A-frag P[16 rows][32 keys]
    const int t = threadIdx.x;
    const int bid = blockIdx.x;
    const int b2 = bid & 255;
    const int h = b2 & 7, kvh = h >> 1;
    const int u = b2 >> 3;                        // 0..31
    const int g = (bid < 256) ? u : 63 - u;       // complementary-work pairing
    const int i0 = g * 64;
    const int w = t >> 6, lid = t & 63, n16 = lid & 15, quad = lid >> 4;
    const int qbase = i0 + w * 16;
    unsigned short* Pw = Ps + w * 512;

    auto stage = [&](int buf, int j0) {
        #pragma unroll
        for (int it = 0; it < 4; ++it) {          // K (16 KiB): 16 frags / 4 waves
            int f = it * 4 + w;                   // wave-uniform frag id
            int nt = f >> 3, ks = f & 7;
            glls16(Kb + (size_t)(j0 + nt * 16 + n16) * KVDIM + kvh * D + ks * 32 + quad * 8,
                   &Ks[buf][f * 512]);
        }
        #pragma unroll
        for (int it = 0; it < 4; ++it) {          // V^T (16 KiB): 16 frags / 4 waves
            int f = it * 4 + w;                   // f = dt
            glls16(Vt + (size_t)(kvh * D + f * 16 + n16) * S + j0 + quad * 8,
                   &Vs[buf][f * 512]);
        }
    };

    // Q A-frags in registers: qf[ks], 16 rows per wave
    short8 qf[8];
    #pragma unroll
    for (int ks = 0; ks < 8; ++ks)
        qf[ks] = *(const short8*)(Qb + (size_t)(qbase + n16) * QDIM + h * D + ks * 32 + quad * 8);

    float m_old[4], l[4];
    #pragma unroll
    for (int rg = 0; rg < 4; ++rg) { m_old[rg] = -INFINITY; l[rg] = 0.f; }
    f32x4 Oacc[16] = {};

    const int jt_min = (i0 >= SW) ? ((i0 - (SW - 1)) >> 5) : 0;
    const int jt_max = (i0 + 63) >> 5;

    stage(0, jt_min * 32);
    int cur = 0;

    for (int jt = jt_min; jt <= jt_max; ++jt) {
        const int j0 = jt * 32;
        asm volatile("s_waitcnt vmcnt(0)" ::: "memory");   // own staging (issued last iter) done
        __syncthreads();                                   // all waves' staging visible
        if (jt < jt_max) stage(cur ^ 1, (jt + 1) * 32);    // prefetch next KV tile

        // ---- S = Q K^T (16 MFMA)
        f32x4 sc[2] = {};
        __builtin_amdgcn_s_setprio(1);
        #pragma unroll
        for (int ks = 0; ks < 8; ++ks) {
            #pragma unroll
            for (int nt = 0; nt < 2; ++nt) {
                short8 kf = *(const short8*)(&Ks[cur][(nt * 8 + ks) * 512 + lid * 8]);
                sc[nt] = __builtin_amdgcn_mfma_f32_16x16x32_bf16(qf[ks], kf, sc[nt], 0, 0, 0);
            }
        }
        __builtin_amdgcn_s_setprio(0);

        // ---- softcap + mask (C layout: key = nt*16+n16, q-row = quad*4+rg)
        #pragma unroll
        for (int nt = 0; nt < 2; ++nt) {
            int j = j0 + nt * 16 + n16;
            #pragma unroll
            for (int rg = 0; rg < 4; ++rg) {
                int iq = qbase + quad * 4 + rg;
                float x = sc[nt][rg];
                float e = __expf(x * (2.0f / SOFTCAP));
                x = SOFTCAP * (1.0f - 2.0f / (e + 1.0f));    // 50*tanh(x/50)
                bool ok = (j <= iq) && (iq - j < SW);
                sc[nt][rg] = ok ? x : -1e9f;
            }
        }

        // ---- online softmax per q-row
        float alpha[4];
        #pragma unroll
        for (int rg = 0; rg < 4; ++rg) {
            float mx = fmaxf(sc[0][rg], sc[1][rg]);
            mx = fmaxf(mx, __shfl_xor(mx, 1));
            mx = fmaxf(mx, __shfl_xor(mx, 2));
            mx = fmaxf(mx, __shfl_xor(mx, 4));
            mx = fmaxf(mx, __shfl_xor(mx, 8));
            float mnew = fmaxf(m_old[rg], mx);
            alpha[rg] = __expf(m_old[rg] - mnew);   // -inf -> 0 first tile
            m_old[rg] = mnew;
        }
        // ---- p = exp(s-m), write P to LDS in A-frag order, accumulate l
        #pragma unroll
        for (int rg = 0; rg < 4; ++rg) {
            float rs = 0.f;
            #pragma unroll
            for (int nt = 0; nt < 2; ++nt) {
                float pv = __expf(sc[nt][rg] - m_old[rg]);
                // A-frag: lane' = row + 16*(key>>3), elem = key&7
                Pw[(quad * 4 + rg + 16 * (nt * 2 + (n16 >> 3))) * 8 + (n16 & 7)]
                    = (unsigned short)f2bf(pv);
                rs += pv;
            }
            rs += __shfl_xor(rs, 1); rs += __shfl_xor(rs, 2);
            rs += __shfl_xor(rs, 4); rs += __shfl_xor(rs, 8);
            l[rg] = l[rg] * alpha[rg] + rs;
        }
        #pragma unroll
        for (int dt = 0; dt < 16; ++dt)
            #pragma unroll
            for (int rg = 0; rg < 4; ++rg)
                Oacc[dt][rg] *= alpha[rg];

        asm volatile("s_waitcnt lgkmcnt(0)" ::: "memory");   // P writes visible (wave-private)

        // ---- O += P V (16 MFMA)
        short8 pf = *(const short8*)(Pw + lid * 8);
        __builtin_amdgcn_s_setprio(1);
        #pragma unroll
        for (int dt = 0; dt < 16; ++dt) {
            short8 vf = *(const short8*)(&Vs[cur][dt * 512 + lid * 8]);
            Oacc[dt] = __builtin_amdgcn_mfma_f32_16x16x32_bf16(pf, vf, Oacc[dt], 0, 0, 0);
        }
        __builtin_amdgcn_s_setprio(0);
        cur ^= 1;
    }

    #pragma unroll
    for (int rg = 0; rg < 4; ++rg) l[rg] = 1.0f / l[rg];
    #pragma unroll
    for (int dt = 0; dt < 16; ++dt) {
        int col = h * D + dt * 16 + n16;
        #pragma unroll
        for (int rg = 0; rg < 4; ++rg) {
            int row = qbase + quad * 4 + rg;
            O[(size_t)row * QDIM + col] = (unsigned short)f2bf(Oacc[dt][rg] * l[rg]);
        }
    }
}

extern "C" void kernel_launch(void* const* d_in, const int* in_sizes, int n_in,
                              void* d_out, int out_size, void* d_ws, size_t ws_size,
                              hipStream_t stream) {
    const float* hidden = (const float*)d_in[0];
    // d_in[1] = attention_mask: recomputed analytically, not read
    const float* Wq = (const float*)d_in[2];
    const float* Wk = (const float*)d_in[3];
    const float* Wv = (const float*)d_in[4];
    const float* Wo = (const float*)d_in[5];
    const int* pos = (const int*)d_in[6];
    float* out = (float*)d_out;

    // workspace layout (85 MiB total, aggressive aliasing):
    //  [0,18M)   Hb  [S][2304] bf16            -> dead after QKV GEMM; Qb [S][2048] (16M) aliases
    //  [18,37M)  Wqkv [4096][2304] bf16 (19M)  -> dead after QKV GEMM; Wo bf16 (9M) aliases
    //  [37,69M)  QKVf [S][4096] bf16 (32M)     -> dead after rope+transpose; Oa (16M) aliases
    //  [69,77M)  Kb  [S][1024] bf16 (8M)
    //  [77,85M)  Vt  [1024][S] bf16 (8M)
    char* ws = (char*)d_ws;
    unsigned short* Hb   = (unsigned short*)(ws);
    unsigned short* Qb   = (unsigned short*)(ws);
    unsigned short* Wqkv = (unsigned short*)(ws + (size_t)(18 << 20));
    unsigned short* QKVf = (unsigned short*)(ws + (size_t)(37 << 20));
    unsigned short* Oa   = (unsigned short*)(ws + (size_t)(37 << 20));
    unsigned short* Kb   = (unsigned short*)(ws + (size_t)(69 << 20));
    unsigned short* Vt   = (unsigned short*)(ws + (size_t)(77 << 20));

    cvt_bf16<<<(S * HID) / 1024, 256, 0, stream>>>(hidden, Hb);
    cvt_bf16<<<(QDIM * HID) / 1024, 256, 0, stream>>>(Wq, Wqkv);
    cvt_bf16<<<(KVDIM * HID) / 1024, 256, 0, stream>>>(Wk, Wqkv + (size_t)QDIM * HID);
    cvt_bf16<<<(KVDIM * HID) / 1024, 256, 0, stream>>>(Wv, Wqkv + (size_t)(QDIM + KVDIM) * HID);

    // fused QKV projection: [4096][2304] @ [4096][2304]^T -> [4096][4096]
    bf16_gemm_bt<unsigned short><<<dim3(QKVDIM / 128, S / 128), 256, 0, stream>>>(
        Hb, Wqkv, QKVf, S, QKVDIM, HID);

    rope_kernel<<<(S * 12 * 128) / 256, 256, 0, stream>>>(QKVf, Qb, Kb, pos);
    transpose_v<<<dim3(S / 64, KVDIM / 64), 256, 0, stream>>>(QKVf, Vt);

    attn_kernel<<<512, 256, 0, stream>>>(Qb, Kb, Vt, Oa);

    cvt_bf16<<<(HID * QDIM) / 1024, 256, 0, stream>>>(Wo, Wqkv);
    bf16_gemm_bt<float><<<dim3(HID / 128, S / 128), 256, 0, stream>>>(Oa, Wqkv, out, S, HID, QDIM);
}

// Round 4
// 591.566 us; speedup vs baseline: 1.3331x; 1.0936x over previous
//
#include <hip/hip_runtime.h>
#include <hip/hip_bf16.h>
#include <math.h>

#define S 4096
#define HQ 8
#define NKVH 4
#define D 256
#define HID 2304
#define SW 2048
#define QDIM 2048
#define KVDIM 1024
#define QKVDIM 4096          // fused Q(2048) | K(1024) | V(1024)
#define SCALE 0.0625f
#define SOFTCAP 50.0f

typedef __attribute__((ext_vector_type(4))) float f32x4;
typedef __attribute__((ext_vector_type(8))) short short8;   // 8 bf16 = 4 VGPRs (MFMA A/B frag)

__device__ __forceinline__ float bf2f(unsigned v) { return __uint_as_float(v << 16); }
__device__ __forceinline__ unsigned f2bf(float f) {
    unsigned u = __float_as_uint(f);
    return (u + 0x7fffu + ((u >> 16) & 1u)) >> 16;   // round-to-nearest-even
}

__device__ __forceinline__ void store_c(float* p, float v) { *p = v; }
__device__ __forceinline__ void store_c(unsigned short* p, float v) { *p = (unsigned short)f2bf(v); }

// async global->LDS, 16B per lane; lds dst is wave-uniform base (HW adds lane*16)
__device__ __forceinline__ void glls16(const void* g, void* l) {
    __builtin_amdgcn_global_load_lds(
        (const __attribute__((address_space(1))) unsigned int*)g,
        (__attribute__((address_space(3))) unsigned int*)l, 16, 0, 0);
}

// ---------------------------------------------------------------------------
// fp32 -> bf16 elementwise (float4 per thread)
// ---------------------------------------------------------------------------
__global__ __launch_bounds__(256) void cvt_bf16(const float* __restrict__ in,
                                                unsigned short* __restrict__ out)
{
    int i = blockIdx.x * 256 + threadIdx.x;
    float4 v = ((const float4*)in)[i];
    uint2 o;
    o.x = f2bf(v.x) | (f2bf(v.y) << 16);
    o.y = f2bf(v.z) | (f2bf(v.w) << 16);
    ((uint2*)out)[i] = o;
}

// ---------------------------------------------------------------------------
// C[M][N] = A[M][K] @ B[N][K]^T, bf16 in, fp32 accumulate, TC out.
// 128x128 tile, BK=64, 256 threads (2x2 waves, 4x4 MFMA tiles, 2 k-substeps).
// Double-buffered LDS, fragment-major, staged via global_load_lds;
// prefetch k+1 while computing k; ONE barrier per k-step.
// Rasterization: bijective XCD chunking, then grouped raster (8 m-tiles per
// band, n sweeps within band) for L2 locality.
// ---------------------------------------------------------------------------
template <typename TC>
__global__ __launch_bounds__(256) void bf16_gemm_bt(const unsigned short* __restrict__ A,
                                                    const unsigned short* __restrict__ B,
                                                    TC* __restrict__ C,
                                                    int M, int N, int K)
{
    __shared__ unsigned short As[2][16 * 512];   // 16 frags x 1 KiB per buffer
    __shared__ unsigned short Bs[2][16 * 512];
    const int t = threadIdx.x;

    // bijective XCD swizzle of the flattened tile id
    const int nbx = gridDim.x;
    const int nwg = nbx * gridDim.y;
    int flat = blockIdx.y * nbx + blockIdx.x;
    const int q8 = nwg >> 3, r8 = nwg & 7;
    const int xcd = flat & 7, orig = flat >> 3;
    const int wg = (xcd < r8 ? xcd * (q8 + 1) : r8 * (q8 + 1) + (xcd - r8) * q8) + orig;
    // grouped raster: bands of 8 m-tiles, n sweeps within a band
    const int band = wg / (8 * nbx);
    const int rem  = wg - band * 8 * nbx;
    const int m0 = (band * 8 + (rem & 7)) * 128;
    const int n0 = (rem >> 3) * 128;

    const int w = t >> 6, lid = t & 63, n16 = lid & 15, quad = lid >> 4;
    const int wm = (w >> 1) * 64, wn = (w & 1) * 64;

    f32x4 acc[4][4] = {};

    // stage buffer `buf` with k-panel starting at k0 (8 glls per wave)
    auto stage = [&](int buf, int k0) {
        #pragma unroll
        for (int it = 0; it < 4; ++it) {
            int f  = it * 4 + w;              // wave-uniform frag id 0..15
            int fm = f >> 1, fk = f & 1;
            const size_t goff = (size_t)(fm * 16 + n16) * K + k0 + fk * 32 + quad * 8;
            glls16(A + (size_t)m0 * K + goff, &As[buf][f * 512]);
            glls16(B + (size_t)n0 * K + goff, &Bs[buf][f * 512]);
        }
    };

    const int nk = K / 64;
    stage(0, 0);
    int cur = 0;
    for (int kk = 0; kk < nk; ++kk) {
        asm volatile("s_waitcnt vmcnt(0)" ::: "memory");   // own staging done
        __syncthreads();                                   // everyone's visible
        if (kk + 1 < nk) stage(cur ^ 1, (kk + 1) * 64);    // prefetch next panel
        #pragma unroll
        for (int ks = 0; ks < 2; ++ks) {
            short8 af[4], bfr[4];
            #pragma unroll
            for (int x = 0; x < 4; ++x) {
                af[x]  = *(const short8*)(&As[cur][(((wm >> 4) + x) * 2 + ks) * 512 + lid * 8]);
                bfr[x] = *(const short8*)(&Bs[cur][(((wn >> 4) + x) * 2 + ks) * 512 + lid * 8]);
            }
            __builtin_amdgcn_s_setprio(1);
            #pragma unroll
            for (int i = 0; i < 4; ++i)
                #pragma unroll
                for (int j = 0; j < 4; ++j)
                    acc[i][j] = __builtin_amdgcn_mfma_f32_16x16x32_bf16(af[i], bfr[j], acc[i][j], 0, 0, 0);
            __builtin_amdgcn_s_setprio(0);
        }
        cur ^= 1;
    }

    // C/D layout: col = lane&15, row = quad*4 + reg
    #pragma unroll
    for (int i = 0; i < 4; ++i) {
        #pragma unroll
        for (int j = 0; j < 4; ++j) {
            int rbase = m0 + wm + i * 16 + quad * 4;
            int col   = n0 + wn + j * 16 + n16;
            #pragma unroll
            for (int rg = 0; rg < 4; ++rg)
                store_c(C + (size_t)(rbase + rg) * N + col, acc[i][j][rg]);
        }
    }
}

// ---------------------------------------------------------------------------
// RoPE: read bf16 Q/K from fused QKV [S][4096] (Q cols 0..2047, K cols
// 2048..3071), write bf16 Qb [S][2048] / Kb [S][1024] (SCALE folded into Q).
// ---------------------------------------------------------------------------
__global__ __launch_bounds__(256) void rope_kernel(const unsigned short* __restrict__ QKV,
                                                   unsigned short* __restrict__ Qb,
                                                   unsigned short* __restrict__ Kb,
                                                   const int* __restrict__ pos_ids)
{
    int id   = blockIdx.x * 256 + threadIdx.x;   // S * 12 * 128 threads
    int d    = id & 127;
    int rest = id >> 7;
    int hh   = rest % 12;
    int i    = rest / 12;
    float pos = (float)pos_ids[i];
    float inv = __expf((float)d * (-9.210340371976184f / 128.0f));   // 10000^(-d/128)
    float ang = pos * inv;
    float sn, cs;
    sincosf(ang, &sn, &cs);
    if (hh < HQ) {
        const unsigned short* p = QKV + (size_t)i * QKVDIM + hh * D + d;
        float x0 = bf2f(p[0]), x1 = bf2f(p[128]);
        unsigned short* q = Qb + (size_t)i * QDIM + hh * D + d;
        q[0]   = (unsigned short)f2bf((x0 * cs - x1 * sn) * SCALE);
        q[128] = (unsigned short)f2bf((x1 * cs + x0 * sn) * SCALE);
    } else {
        const unsigned short* p = QKV + (size_t)i * QKVDIM + QDIM + (hh - HQ) * D + d;
        float x0 = bf2f(p[0]), x1 = bf2f(p[128]);
        unsigned short* k = Kb + (size_t)i * KVDIM + (hh - HQ) * D + d;
        k[0]   = (unsigned short)f2bf(x0 * cs - x1 * sn);
        k[128] = (unsigned short)f2bf(x1 * cs + x0 * sn);
    }
}

// ---------------------------------------------------------------------------
// V transpose: fused QKV [S][4096] cols 3072..4095 -> Vt [KVDIM][S] bf16.
// ---------------------------------------------------------------------------
__global__ __launch_bounds__(256) void transpose_v(const unsigned short* __restrict__ QKV,
                                                   unsigned short* __restrict__ Vt)
{
    __shared__ float tile[64][65];
    const int s0 = blockIdx.x * 64, d0 = blockIdx.y * 64;
    const int t = threadIdx.x;
    #pragma unroll
    for (int it = 0; it < 4; ++it) {
        int flat = it * 256 + t;
        int r  = flat >> 4;
        int c4 = (flat & 15) * 4;
        uint2 v = *(const uint2*)(QKV + (size_t)(s0 + r) * QKVDIM + (QDIM + KVDIM) + d0 + c4);
        tile[r][c4 + 0] = bf2f(v.x & 0xffffu); tile[r][c4 + 1] = bf2f(v.x >> 16);
        tile[r][c4 + 2] = bf2f(v.y & 0xffffu); tile[r][c4 + 3] = bf2f(v.y >> 16);
    }
    __syncthreads();
    #pragma unroll
    for (int it = 0; it < 4; ++it) {
        int flat = it * 256 + t;
        int dr  = flat >> 4;
        int sc4 = (flat & 15) * 4;
        uint2 o;
        o.x = f2bf(tile[sc4 + 0][dr]) | (f2bf(tile[sc4 + 1][dr]) << 16);
        o.y = f2bf(tile[sc4 + 2][dr]) | (f2bf(tile[sc4 + 3][dr]) << 16);
        *(uint2*)(Vt + (size_t)(d0 + dr) * S + s0 + sc4) = o;
    }
}

// ---------------------------------------------------------------------------
// MFMA flash attention with FIXED-MAX softmax.
// Softcap bounds post-cap scores to [-50,50], so m=50 is a valid softmax
// shift: p = exp(t-50) = exp(-100/(exp(2s/50)+1))  (exact identity).
// => NO running max, NO alpha rescale, NO in-loop cross-lane reduces.
// l is a plain sum: per-lane partials in-loop, ONE 4-shuffle reduce at end.
// p underflows to 0 only for s < -50 (~60 sigma); diagonal keeps l > 0.
// Block = 256 threads (4 waves), 64 q-rows (16/wave), ONE head per block.
// Grid 512, h = bid&7 (XCD-affine KV in L2). KV tiles of 32 keys, K/V
// double-buffered via global_load_lds, tile j+1 prefetched while computing j.
// LDS = 68 KiB => 2 blocks/CU.
// ---------------------------------------------------------------------------
__global__ __launch_bounds__(256, 2) void attn_kernel(const unsigned short* __restrict__ Qb,
                                                      const unsigned short* __restrict__ Kb,
                                                      const unsigned short* __restrict__ Vt,
                                                      unsigned short* __restrict__ O)
{
    __shared__ unsigned short Ks[2][32 * 256];   // 16 frags: f=nt*8+ks -> K[key=nt*16+n16][k=ks*32+quad*8]
    __shared__ unsigned short Vs[2][256 * 32];   // 16 frags: f=dt      -> Vt[d=dt*16+n16][key=quad*8]
    __shared__ unsigned short Ps[4 * 512];       // per-wave A-frag P[16 rows][32 keys]
    const int t = threadIdx.x;
    const int bid = blockIdx.x;
    const int b2 = bid & 255;
    const int h = b2 & 7, kvh = h >> 1;
    const int u = b2 >> 3;                        // 0..31
    const int g = (bid < 256) ? u : 63 - u;
    const int i0 = g * 64;
    const int w = t >> 6, lid = t & 63, n16 = lid & 15, quad = lid >> 4;
    const int qbase = i0 + w * 16;
    unsigned short* Pw = Ps + w * 512;

    auto stage = [&](int buf, int j0) {
        #pragma unroll
        for (int it = 0; it < 4; ++it) {          // K (16 KiB): 16 frags / 4 waves
            int f = it * 4 + w;                   // wave-uniform frag id
            int nt = f >> 3, ks = f & 7;
            glls16(Kb + (size_t)(j0 + nt * 16 + n16) * KVDIM + kvh * D + ks * 32 + quad * 8,
                   &Ks[buf][f * 512]);
        }
        #pragma unroll
        for (int it = 0; it < 4; ++it) {          // V^T (16 KiB): 16 frags / 4 waves
            int f = it * 4 + w;                   // f = dt
            glls16(Vt + (size_t)(kvh * D + f * 16 + n16) * S + j0 + quad * 8,
                   &Vs[buf][f * 512]);
        }
    };

    // Q A-frags in registers: qf[ks], 16 rows per wave
    short8 qf[8];
    #pragma unroll
    for (int ks = 0; ks < 8; ++ks)
        qf[ks] = *(const short8*)(Qb + (size_t)(qbase + n16) * QDIM + h * D + ks * 32 + quad * 8);

    float lacc[4] = {0.f, 0.f, 0.f, 0.f};        // per-lane partial row-sums
    f32x4 Oacc[16] = {};

    const int jt_min = (i0 >= SW) ? ((i0 - (SW - 1)) >> 5) : 0;
    const int jt_max = (i0 + 63) >> 5;

    stage(0, jt_min * 32);
    int cur = 0;

    for (int jt = jt_min; jt <= jt_max; ++jt) {
        const int j0 = jt * 32;
        asm volatile("s_waitcnt vmcnt(0)" ::: "memory");   // own staging (issued last iter) done
        __syncthreads();                                   // all waves' staging visible
        if (jt < jt_max) stage(cur ^ 1, (jt + 1) * 32);    // prefetch next KV tile

        // ---- S = Q K^T (16 MFMA)
        f32x4 sc[2] = {};
        __builtin_amdgcn_s_setprio(1);
        #pragma unroll
        for (int ks = 0; ks < 8; ++ks) {
            #pragma unroll
            for (int nt = 0; nt < 2; ++nt) {
                short8 kf = *(const short8*)(&Ks[cur][(nt * 8 + ks) * 512 + lid * 8]);
                sc[nt] = __builtin_amdgcn_mfma_f32_16x16x32_bf16(qf[ks], kf, sc[nt], 0, 0, 0);
            }
        }
        __builtin_amdgcn_s_setprio(0);

        // ---- fused softcap + fixed-max softmax (C layout: key = nt*16+n16,
        // q-row = quad*4+rg):  p = exp(-100/(exp(2s/50)+1)), masked -> 0
        #pragma unroll
        for (int nt = 0; nt < 2; ++nt) {
            int j = j0 + nt * 16 + n16;
            #pragma unroll
            for (int rg = 0; rg < 4; ++rg) {
                int iq = qbase + quad * 4 + rg;
                float e = __expf(sc[nt][rg] * (2.0f / SOFTCAP));
                float p = __expf(-100.0f * __builtin_amdgcn_rcpf(e + 1.0f));
                bool ok = (j <= iq) && (iq - j < SW);
                p = ok ? p : 0.0f;
                lacc[rg] += p;
                // A-frag: lane' = row + 16*(key>>3), elem = key&7
                Pw[(quad * 4 + rg + 16 * (nt * 2 + (n16 >> 3))) * 8 + (n16 & 7)]
                    = (unsigned short)f2bf(p);
            }
        }

        asm volatile("s_waitcnt lgkmcnt(0)" ::: "memory");   // P writes visible (wave-private)

        // ---- O += P V (16 MFMA)
        short8 pf = *(const short8*)(Pw + lid * 8);
        __builtin_amdgcn_s_setprio(1);
        #pragma unroll
        for (int dt = 0; dt < 16; ++dt) {
            short8 vf = *(const short8*)(&Vs[cur][dt * 512 + lid * 8]);
            Oacc[dt] = __builtin_amdgcn_mfma_f32_16x16x32_bf16(pf, vf, Oacc[dt], 0, 0, 0);
        }
        __builtin_amdgcn_s_setprio(0);
        cur ^= 1;
    }

    // final row-sum reduce across the 16 key-lanes (once, not per tile)
    float linv[4];
    #pragma unroll
    for (int rg = 0; rg < 4; ++rg) {
        float rs = lacc[rg];
        rs += __shfl_xor(rs, 1); rs += __shfl_xor(rs, 2);
        rs += __shfl_xor(rs, 4); rs += __shfl_xor(rs, 8);
        linv[rg] = 1.0f / rs;
    }
    #pragma unroll
    for (int dt = 0; dt < 16; ++dt) {
        int col = h * D + dt * 16 + n16;
        #pragma unroll
        for (int rg = 0; rg < 4; ++rg) {
            int row = qbase + quad * 4 + rg;
            O[(size_t)row * QDIM + col] = (unsigned short)f2bf(Oacc[dt][rg] * linv[rg]);
        }
    }
}

extern "C" void kernel_launch(void* const* d_in, const int* in_sizes, int n_in,
                              void* d_out, int out_size, void* d_ws, size_t ws_size,
                              hipStream_t stream) {
    const float* hidden = (const float*)d_in[0];
    // d_in[1] = attention_mask: recomputed analytically, not read
    const float* Wq = (const float*)d_in[2];
    const float* Wk = (const float*)d_in[3];
    const float* Wv = (const float*)d_in[4];
    const float* Wo = (const float*)d_in[5];
    const int* pos = (const int*)d_in[6];
    float* out = (float*)d_out;

    // workspace layout (85 MiB total, aggressive aliasing):
    //  [0,18M)   Hb  [S][2304] bf16            -> dead after QKV GEMM; Qb [S][2048] (16M) aliases
    //  [18,37M)  Wqkv [4096][2304] bf16 (19M)  -> dead after QKV GEMM; Wo bf16 (9M) aliases
    //  [37,69M)  QKVf [S][4096] bf16 (32M)     -> dead after rope+transpose; Oa (16M) aliases
    //  [69,77M)  Kb  [S][1024] bf16 (8M)
    //  [77,85M)  Vt  [1024][S] bf16 (8M)
    char* ws = (char*)d_ws;
    unsigned short* Hb   = (unsigned short*)(ws);
    unsigned short* Qb   = (unsigned short*)(ws);
    unsigned short* Wqkv = (unsigned short*)(ws + (size_t)(18 << 20));
    unsigned short* QKVf = (unsigned short*)(ws + (size_t)(37 << 20));
    unsigned short* Oa   = (unsigned short*)(ws + (size_t)(37 << 20));
    unsigned short* Kb   = (unsigned short*)(ws + (size_t)(69 << 20));
    unsigned short* Vt   = (unsigned short*)(ws + (size_t)(77 << 20));

    cvt_bf16<<<(S * HID) / 1024, 256, 0, stream>>>(hidden, Hb);
    cvt_bf16<<<(QDIM * HID) / 1024, 256, 0, stream>>>(Wq, Wqkv);
    cvt_bf16<<<(KVDIM * HID) / 1024, 256, 0, stream>>>(Wk, Wqkv + (size_t)QDIM * HID);
    cvt_bf16<<<(KVDIM * HID) / 1024, 256, 0, stream>>>(Wv, Wqkv + (size_t)(QDIM + KVDIM) * HID);

    // fused QKV projection: [4096][2304] @ [4096][2304]^T -> [4096][4096]
    bf16_gemm_bt<unsigned short><<<dim3(QKVDIM / 128, S / 128), 256, 0, stream>>>(
        Hb, Wqkv, QKVf, S, QKVDIM, HID);

    rope_kernel<<<(S * 12 * 128) / 256, 256, 0, stream>>>(QKVf, Qb, Kb, pos);
    transpose_v<<<dim3(S / 64, KVDIM / 64), 256, 0, stream>>>(QKVf, Vt);

    attn_kernel<<<512, 256, 0, stream>>>(Qb, Kb, Vt, Oa);

    cvt_bf16<<<(HID * QDIM) / 1024, 256, 0, stream>>>(Wo, Wqkv);
    bf16_gemm_bt<float><<<dim3(HID / 128, S / 128), 256, 0, stream>>>(Oa, Wqkv, out, S, HID, QDIM);
}

// Round 6
// 568.699 us; speedup vs baseline: 1.3867x; 1.0402x over previous
//
#include <hip/hip_runtime.h>
#include <hip/hip_bf16.h>
#include <math.h>

#define S 4096
#define HQ 8
#define NKVH 4
#define D 256
#define HID 2304
#define SW 2048
#define QDIM 2048
#define KVDIM 1024
#define QKVDIM 4096          // fused Q(2048) | K(1024) | V(1024)
#define SCALE 0.0625f
#define SOFTCAP 50.0f

typedef __attribute__((ext_vector_type(4))) float f32x4;
typedef __attribute__((ext_vector_type(8))) short short8;   // 8 bf16 = 4 VGPRs (MFMA A/B frag)

__device__ __forceinline__ float bf2f(unsigned v) { return __uint_as_float(v << 16); }
__device__ __forceinline__ unsigned f2bf(float f) {
    unsigned u = __float_as_uint(f);
    return (u + 0x7fffu + ((u >> 16) & 1u)) >> 16;   // round-to-nearest-even
}

__device__ __forceinline__ void store_c(float* p, float v) { *p = v; }
__device__ __forceinline__ void store_c(unsigned short* p, float v) { *p = (unsigned short)f2bf(v); }

// async global->LDS, 16B per lane; lds dst is wave-uniform base (HW adds lane*16)
__device__ __forceinline__ void glls16(const void* g, void* l) {
    __builtin_amdgcn_global_load_lds(
        (const __attribute__((address_space(1))) unsigned int*)g,
        (__attribute__((address_space(3))) unsigned int*)l, 16, 0, 0);
}

// ---------------------------------------------------------------------------
// fp32 -> bf16 elementwise (float4 per thread)
// ---------------------------------------------------------------------------
__global__ __launch_bounds__(256) void cvt_bf16(const float* __restrict__ in,
                                                unsigned short* __restrict__ out)
{
    int i = blockIdx.x * 256 + threadIdx.x;
    float4 v = ((const float4*)in)[i];
    uint2 o;
    o.x = f2bf(v.x) | (f2bf(v.y) << 16);
    o.y = f2bf(v.z) | (f2bf(v.w) << 16);
    ((uint2*)out)[i] = o;
}

// ---------------------------------------------------------------------------
// 128x128-tile GEMM (verified m97-style structure) — kept for O-projection.
// C[M][N] = A[M][K] @ B[N][K]^T, bf16 in, fp32 accumulate, TC out.
// ---------------------------------------------------------------------------
template <typename TC>
__global__ __launch_bounds__(256) void bf16_gemm_bt(const unsigned short* __restrict__ A,
                                                    const unsigned short* __restrict__ B,
                                                    TC* __restrict__ C,
                                                    int M, int N, int K)
{
    __shared__ unsigned short As[2][16 * 512];   // 16 frags x 1 KiB per buffer
    __shared__ unsigned short Bs[2][16 * 512];
    const int t = threadIdx.x;

    // bijective XCD swizzle of the flattened tile id
    const int nbx = gridDim.x;
    const int nwg = nbx * gridDim.y;
    int flat = blockIdx.y * nbx + blockIdx.x;
    const int q8 = nwg >> 3, r8 = nwg & 7;
    const int xcd = flat & 7, orig = flat >> 3;
    const int wg = (xcd < r8 ? xcd * (q8 + 1) : r8 * (q8 + 1) + (xcd - r8) * q8) + orig;
    // grouped raster: bands of 8 m-tiles, n sweeps within a band
    const int band = wg / (8 * nbx);
    const int rem  = wg - band * 8 * nbx;
    const int m0 = (band * 8 + (rem & 7)) * 128;
    const int n0 = (rem >> 3) * 128;

    const int w = t >> 6, lid = t & 63, n16 = lid & 15, quad = lid >> 4;
    const int wm = (w >> 1) * 64, wn = (w & 1) * 64;

    f32x4 acc[4][4] = {};

    auto stage = [&](int buf, int k0) {
        #pragma unroll
        for (int it = 0; it < 4; ++it) {
            int f  = it * 4 + w;              // wave-uniform frag id 0..15
            int fm = f >> 1, fk = f & 1;
            const size_t goff = (size_t)(fm * 16 + n16) * K + k0 + fk * 32 + quad * 8;
            glls16(A + (size_t)m0 * K + goff, &As[buf][f * 512]);
            glls16(B + (size_t)n0 * K + goff, &Bs[buf][f * 512]);
        }
    };

    const int nk = K / 64;
    stage(0, 0);
    int cur = 0;
    for (int kk = 0; kk < nk; ++kk) {
        asm volatile("s_waitcnt vmcnt(0)" ::: "memory");   // own staging done
        __syncthreads();                                   // everyone's visible
        if (kk + 1 < nk) stage(cur ^ 1, (kk + 1) * 64);    // prefetch next panel
        #pragma unroll
        for (int ks = 0; ks < 2; ++ks) {
            short8 af[4], bfr[4];
            #pragma unroll
            for (int x = 0; x < 4; ++x) {
                af[x]  = *(const short8*)(&As[cur][(((wm >> 4) + x) * 2 + ks) * 512 + lid * 8]);
                bfr[x] = *(const short8*)(&Bs[cur][(((wn >> 4) + x) * 2 + ks) * 512 + lid * 8]);
            }
            __builtin_amdgcn_s_setprio(1);
            #pragma unroll
            for (int i = 0; i < 4; ++i)
                #pragma unroll
                for (int j = 0; j < 4; ++j)
                    acc[i][j] = __builtin_amdgcn_mfma_f32_16x16x32_bf16(af[i], bfr[j], acc[i][j], 0, 0, 0);
            __builtin_amdgcn_s_setprio(0);
        }
        cur ^= 1;
    }

    #pragma unroll
    for (int i = 0; i < 4; ++i) {
        #pragma unroll
        for (int j = 0; j < 4; ++j) {
            int rbase = m0 + wm + i * 16 + quad * 4;
            int col   = n0 + wn + j * 16 + n16;
            #pragma unroll
            for (int rg = 0; rg < 4; ++rg)
                store_c(C + (size_t)(rbase + rg) * N + col, acc[i][j][rg]);
        }
    }
}

// ---------------------------------------------------------------------------
// 256x256-tile 8-phase GEMM (T3+T4: counted vmcnt), bf16->bf16. 512 threads =
// 8 waves (2m x 4n), per-wave output 128x64, BK=64, 2 K-tiles/iteration.
// Fragment-major LDS (frag = 16 rows x 32 k = 1 KiB, staged linearly by one
// wave's global_load_lds, read as contiguous per-wave ds_read_b128) =>
// conflict-free without byte-swizzle. LDS = 128 KiB, 1 block/CU.
//
// Phases are (mh,nh) output quadrants. Read sets per buffer:
//   mh0 phases (1,2 / 5,6) read A-frags {0..3, 8..11}  ("A-mh0 set")
//   mh1 phases (3,4 / 7,8) read A-frags {4..7, 12..15} ("A-mh1 set")
//   nh0 phases (1,3 / 5,7) read B-frags {0,1,4,5,8,9,12,13} ("B-nh0 set")
//   nh1 phases (2,4 / 6,8) read B-frags {2,3,6,7,10,11,14,15} ("B-nh1 set")
// Staging schedule (each region staged strictly AFTER its last reader's
// closing barrier; verified region-by-region):
//   ph1: b1.A-mh1(t2I+1)  ph2: b1.B-nh1(t2I+1)
//   ph3: b0.A-mh0(t2I+2)  ph4: b0.B-nh0(t2I+2) + vmcnt(4)  [gates ph5 b1 reads]
//   ph5: b0.A-mh1(t2I+2)  ph6: b0.B-nh1(t2I+2)
//   ph7: b1.A-mh0(t2I+3)  ph8: b1.B-nh0(t2I+3) + vmcnt(4)  [gates ph1' b0 reads]
// Per-wave ledger: 2 glls/phase; steady-state carry 4 outstanding at ph1;
// at ph4/ph8: 12 outstanding, need oldest 8 done -> vmcnt(4). Prologue: 12
// issued, need first 8 (all of b0) -> vmcnt(4). Peeled last iter: vmcnt(0)
// at ph4. Wave-local wait + s_barrier => collective visibility.
// ---------------------------------------------------------------------------
__global__ __launch_bounds__(512, 2) void bf16_gemm_8ph(const unsigned short* __restrict__ A,
                                                        const unsigned short* __restrict__ B,
                                                        unsigned short* __restrict__ C,
                                                        int M, int N, int K)
{
    __shared__ unsigned short As[2][32 * 512];   // 32 frags (16 m x 2 ks) x 1 KiB
    __shared__ unsigned short Bs[2][32 * 512];   // 32 frags (16 n x 2 ks) x 1 KiB
    const int t = threadIdx.x;
    const int w = t >> 6, lid = t & 63, n16 = lid & 15, quad = lid >> 4;

    // XCD chunk swizzle (grid = 256, 32 blocks/XCD contiguous)
    const int flat = blockIdx.x;
    const int wg = (flat & 7) * 32 + (flat >> 3);
    const int m0 = (wg >> 4) * 256, n0 = (wg & 15) * 256;

    const int wmf = (w >> 2) * 8;             // wave m-frag base (0 or 8)
    const int wnf = (w & 3) * 4;              // wave n-frag base (0,4,8,12)
    const int fnw = (w >> 1) * 4 + (w & 1);   // B nh0 staging frag for this wave

    f32x4 acc[8][4] = {};

    auto stageA = [&](int buf, int k0, int fm) {
        glls16(A + (size_t)(m0 + fm * 16 + n16) * K + k0 + quad * 8,
               &As[buf][(fm * 2 + 0) * 512]);
        glls16(A + (size_t)(m0 + fm * 16 + n16) * K + k0 + 32 + quad * 8,
               &As[buf][(fm * 2 + 1) * 512]);
    };
    auto stageB = [&](int buf, int k0, int fn) {
        glls16(B + (size_t)(n0 + fn * 16 + n16) * K + k0 + quad * 8,
               &Bs[buf][(fn * 2 + 0) * 512]);
        glls16(B + (size_t)(n0 + fn * 16 + n16) * K + k0 + 32 + quad * 8,
               &Bs[buf][(fn * 2 + 1) * 512]);
    };
    // bijective wave->frag assignments matching the read sets:
    auto sAm0 = [&](int buf, int k0){ stageA(buf, k0, (w & 3) + (w >> 2) * 8); };      // {0..3, 8..11}
    auto sAm1 = [&](int buf, int k0){ stageA(buf, k0, 4 + (w & 3) + (w >> 2) * 8); };  // {4..7, 12..15}
    auto sBn0 = [&](int buf, int k0){ stageB(buf, k0, fnw); };                          // {0,1,4,5,8,9,12,13}
    auto sBn1 = [&](int buf, int k0){ stageB(buf, k0, fnw + 2); };                      // {2,3,6,7,10,11,14,15}

#define GPHASE(mh, nh, buf, STAGE, WAITSTR)                                          \
    {                                                                                \
        short8 afr[4][2], bfr[2][2];                                                 \
        _Pragma("unroll") for (int i = 0; i < 4; ++i)                                \
            _Pragma("unroll") for (int ks = 0; ks < 2; ++ks)                         \
                afr[i][ks] = *(const short8*)(&As[buf][((wmf + (mh)*4 + i)*2 + ks)*512 + lid*8]); \
        _Pragma("unroll") for (int j = 0; j < 2; ++j)                                \
            _Pragma("unroll") for (int ks = 0; ks < 2; ++ks)                         \
                bfr[j][ks] = *(const short8*)(&Bs[buf][((wnf + (nh)*2 + j)*2 + ks)*512 + lid*8]); \
        STAGE;                                                                       \
        __builtin_amdgcn_s_barrier();                                                \
        asm volatile("s_waitcnt lgkmcnt(0)" ::: "memory");                           \
        __builtin_amdgcn_sched_barrier(0);                                           \
        __builtin_amdgcn_s_setprio(1);                                               \
        _Pragma("unroll") for (int i = 0; i < 4; ++i)                                \
            _Pragma("unroll") for (int j = 0; j < 2; ++j)                            \
                _Pragma("unroll") for (int ks = 0; ks < 2; ++ks)                     \
                    acc[(mh)*4 + i][(nh)*2 + j] = __builtin_amdgcn_mfma_f32_16x16x32_bf16( \
                        afr[i][ks], bfr[j][ks], acc[(mh)*4 + i][(nh)*2 + j], 0, 0, 0); \
        __builtin_amdgcn_s_setprio(0);                                               \
        asm volatile(WAITSTR ::: "memory");                                          \
        __builtin_amdgcn_s_barrier();                                                \
    }

    const int nk = K / 64;            // 2304/64 = 36
    const int niter = nk / 2;         // 18

    // prologue: all of b0 (tile 0), then b1.A-mh0 + b1.B-nh0 (tile 1)
    sAm0(0, 0); sBn0(0, 0); sAm1(0, 0); sBn1(0, 0);
    sAm0(1, 64); sBn0(1, 64);
    asm volatile("s_waitcnt vmcnt(4)" ::: "memory");   // first 8 glls (= all b0) done
    __builtin_amdgcn_s_barrier();

    for (int I = 0; I < niter - 1; ++I) {
        const int kc = I * 128;       // tile 2I at kc (b0), 2I+1 at kc+64 (b1)
        GPHASE(0, 0, 0, sAm1(1, kc + 64);,  "")
        GPHASE(0, 1, 0, sBn1(1, kc + 64);,  "")
        GPHASE(1, 0, 0, sAm0(0, kc + 128);, "")
        GPHASE(1, 1, 0, sBn0(0, kc + 128);, "s_waitcnt vmcnt(4)")
        GPHASE(0, 0, 1, sAm1(0, kc + 128);, "")
        GPHASE(0, 1, 1, sBn1(0, kc + 128);, "")
        GPHASE(1, 0, 1, sAm0(1, kc + 192);, "")
        GPHASE(1, 1, 1, sBn0(1, kc + 192);, "s_waitcnt vmcnt(4)")
    }
    // peeled last iteration: finish b1 (tile nk-1) in ph1/ph2, drain at ph4
    {
        const int kc = (niter - 1) * 128;
        GPHASE(0, 0, 0, sAm1(1, kc + 64);, "")
        GPHASE(0, 1, 0, sBn1(1, kc + 64);, "")
        GPHASE(1, 0, 0, {};,               "")
        GPHASE(1, 1, 0, {};,               "s_waitcnt vmcnt(0)")
        GPHASE(0, 0, 1, {};,               "")
        GPHASE(0, 1, 1, {};,               "")
        GPHASE(1, 0, 1, {};,               "")
        GPHASE(1, 1, 1, {};,               "")
    }
#undef GPHASE

    // C-write: rows m0 + (w>>2)*128 + mi*16 + quad*4 + rg; cols n0 + (w&3)*64 + nj*16 + n16
    #pragma unroll
    for (int mi = 0; mi < 8; ++mi) {
        #pragma unroll
        for (int nj = 0; nj < 4; ++nj) {
            int rbase = m0 + (w >> 2) * 128 + mi * 16 + quad * 4;
            int col   = n0 + (w & 3) * 64 + nj * 16 + n16;
            #pragma unroll
            for (int rg = 0; rg < 4; ++rg)
                store_c(C + (size_t)(rbase + rg) * N + col, acc[mi][nj][rg]);
        }
    }
}

// ---------------------------------------------------------------------------
// RoPE: read bf16 Q/K from fused QKV [S][4096], write Qb/Kb (SCALE folded).
// ---------------------------------------------------------------------------
__global__ __launch_bounds__(256) void rope_kernel(const unsigned short* __restrict__ QKV,
                                                   unsigned short* __restrict__ Qb,
                                                   unsigned short* __restrict__ Kb,
                                                   const int* __restrict__ pos_ids)
{
    int id   = blockIdx.x * 256 + threadIdx.x;   // S * 12 * 128 threads
    int d    = id & 127;
    int rest = id >> 7;
    int hh   = rest % 12;
    int i    = rest / 12;
    float pos = (float)pos_ids[i];
    float inv = __expf((float)d * (-9.210340371976184f / 128.0f));   // 10000^(-d/128)
    float ang = pos * inv;
    float sn, cs;
    sincosf(ang, &sn, &cs);
    if (hh < HQ) {
        const unsigned short* p = QKV + (size_t)i * QKVDIM + hh * D + d;
        float x0 = bf2f(p[0]), x1 = bf2f(p[128]);
        unsigned short* q = Qb + (size_t)i * QDIM + hh * D + d;
        q[0]   = (unsigned short)f2bf((x0 * cs - x1 * sn) * SCALE);
        q[128] = (unsigned short)f2bf((x1 * cs + x0 * sn) * SCALE);
    } else {
        const unsigned short* p = QKV + (size_t)i * QKVDIM + QDIM + (hh - HQ) * D + d;
        float x0 = bf2f(p[0]), x1 = bf2f(p[128]);
        unsigned short* k = Kb + (size_t)i * KVDIM + (hh - HQ) * D + d;
        k[0]   = (unsigned short)f2bf(x0 * cs - x1 * sn);
        k[128] = (unsigned short)f2bf(x1 * cs + x0 * sn);
    }
}

// ---------------------------------------------------------------------------
// V transpose: fused QKV [S][4096] cols 3072..4095 -> Vt [KVDIM][S] bf16.
// ---------------------------------------------------------------------------
__global__ __launch_bounds__(256) void transpose_v(const unsigned short* __restrict__ QKV,
                                                   unsigned short* __restrict__ Vt)
{
    __shared__ float tile[64][65];
    const int s0 = blockIdx.x * 64, d0 = blockIdx.y * 64;
    const int t = threadIdx.x;
    #pragma unroll
    for (int it = 0; it < 4; ++it) {
        int flat = it * 256 + t;
        int r  = flat >> 4;
        int c4 = (flat & 15) * 4;
        uint2 v = *(const uint2*)(QKV + (size_t)(s0 + r) * QKVDIM + (QDIM + KVDIM) + d0 + c4);
        tile[r][c4 + 0] = bf2f(v.x & 0xffffu); tile[r][c4 + 1] = bf2f(v.x >> 16);
        tile[r][c4 + 2] = bf2f(v.y & 0xffffu); tile[r][c4 + 3] = bf2f(v.y >> 16);
    }
    __syncthreads();
    #pragma unroll
    for (int it = 0; it < 4; ++it) {
        int flat = it * 256 + t;
        int dr  = flat >> 4;
        int sc4 = (flat & 15) * 4;
        uint2 o;
        o.x = f2bf(tile[sc4 + 0][dr]) | (f2bf(tile[sc4 + 1][dr]) << 16);
        o.y = f2bf(tile[sc4 + 2][dr]) | (f2bf(tile[sc4 + 3][dr]) << 16);
        *(uint2*)(Vt + (size_t)(d0 + dr) * S + s0 + sc4) = o;
    }
}

// ---------------------------------------------------------------------------
// MFMA flash attention with FIXED-MAX softmax (see R4 notes): softcap bounds
// scores to [-50,50] so p = exp(t-50) = exp(-100/(exp(2s/50)+1)) exactly —
// no running max, no rescale, l reduced once after the loop.
// ---------------------------------------------------------------------------
__global__ __launch_bounds__(256, 2) void attn_kernel(const unsigned short* __restrict__ Qb,
                                                      const unsigned short* __restrict__ Kb,
                                                      const unsigned short* __restrict__ Vt,
                                                      unsigned short* __restrict__ O)
{
    __shared__ unsigned short Ks[2][32 * 256];
    __shared__ unsigned short Vs[2][256 * 32];
    __shared__ unsigned short Ps[4 * 512];
    const int t = threadIdx.x;
    const int bid = blockIdx.x;
    const int b2 = bid & 255;
    const int h = b2 & 7, kvh = h >> 1;
    const int u = b2 >> 3;
    const int g = (bid < 256) ? u : 63 - u;
    const int i0 = g * 64;
    const int w = t >> 6, lid = t & 63, n16 = lid & 15, quad = lid >> 4;
    const int qbase = i0 + w * 16;
    unsigned short* Pw = Ps + w * 512;

    auto stage = [&](int buf, int j0) {
        #pragma unroll
        for (int it = 0; it < 4; ++it) {
            int f = it * 4 + w;
            int nt = f >> 3, ks = f & 7;
            glls16(Kb + (size_t)(j0 + nt * 16 + n16) * KVDIM + kvh * D + ks * 32 + quad * 8,
                   &Ks[buf][f * 512]);
        }
        #pragma unroll
        for (int it = 0; it < 4; ++it) {
            int f = it * 4 + w;
            glls16(Vt + (size_t)(kvh * D + f * 16 + n16) * S + j0 + quad * 8,
                   &Vs[buf][f * 512]);
        }
    };

    short8 qf[8];
    #pragma unroll
    for (int ks = 0; ks < 8; ++ks)
        qf[ks] = *(const short8*)(Qb + (size_t)(qbase + n16) * QDIM + h * D + ks * 32 + quad * 8);

    float lacc[4] = {0.f, 0.f, 0.f, 0.f};
    f32x4 Oacc[16] = {};

    const int jt_min = (i0 >= SW) ? ((i0 - (SW - 1)) >> 5) : 0;
    const int jt_max = (i0 + 63) >> 5;

    stage(0, jt_min * 32);
    int cur = 0;

    for (int jt = jt_min; jt <= jt_max; ++jt) {
        const int j0 = jt * 32;
        asm volatile("s_waitcnt vmcnt(0)" ::: "memory");
        __syncthreads();
        if (jt < jt_max) stage(cur ^ 1, (jt + 1) * 32);

        f32x4 sc[2] = {};
        __builtin_amdgcn_s_setprio(1);
        #pragma unroll
        for (int ks = 0; ks < 8; ++ks) {
            #pragma unroll
            for (int nt = 0; nt < 2; ++nt) {
                short8 kf = *(const short8*)(&Ks[cur][(nt * 8 + ks) * 512 + lid * 8]);
                sc[nt] = __builtin_amdgcn_mfma_f32_16x16x32_bf16(qf[ks], kf, sc[nt], 0, 0, 0);
            }
        }
        __builtin_amdgcn_s_setprio(0);

        #pragma unroll
        for (int nt = 0; nt < 2; ++nt) {
            int j = j0 + nt * 16 + n16;
            #pragma unroll
            for (int rg = 0; rg < 4; ++rg) {
                int iq = qbase + quad * 4 + rg;
                float e = __expf(sc[nt][rg] * (2.0f / SOFTCAP));
                float p = __expf(-100.0f * __builtin_amdgcn_rcpf(e + 1.0f));
                bool ok = (j <= iq) && (iq - j < SW);
                p = ok ? p : 0.0f;
                lacc[rg] += p;
                Pw[(quad * 4 + rg + 16 * (nt * 2 + (n16 >> 3))) * 8 + (n16 & 7)]
                    = (unsigned short)f2bf(p);
            }
        }

        asm volatile("s_waitcnt lgkmcnt(0)" ::: "memory");

        short8 pf = *(const short8*)(Pw + lid * 8);
        __builtin_amdgcn_s_setprio(1);
        #pragma unroll
        for (int dt = 0; dt < 16; ++dt) {
            short8 vf = *(const short8*)(&Vs[cur][dt * 512 + lid * 8]);
            Oacc[dt] = __builtin_amdgcn_mfma_f32_16x16x32_bf16(pf, vf, Oacc[dt], 0, 0, 0);
        }
        __builtin_amdgcn_s_setprio(0);
        cur ^= 1;
    }

    float linv[4];
    #pragma unroll
    for (int rg = 0; rg < 4; ++rg) {
        float rs = lacc[rg];
        rs += __shfl_xor(rs, 1); rs += __shfl_xor(rs, 2);
        rs += __shfl_xor(rs, 4); rs += __shfl_xor(rs, 8);
        linv[rg] = 1.0f / rs;
    }
    #pragma unroll
    for (int dt = 0; dt < 16; ++dt) {
        int col = h * D + dt * 16 + n16;
        #pragma unroll
        for (int rg = 0; rg < 4; ++rg) {
            int row = qbase + quad * 4 + rg;
            O[(size_t)row * QDIM + col] = (unsigned short)f2bf(Oacc[dt][rg] * linv[rg]);
        }
    }
}

extern "C" void kernel_launch(void* const* d_in, const int* in_sizes, int n_in,
                              void* d_out, int out_size, void* d_ws, size_t ws_size,
                              hipStream_t stream) {
    const float* hidden = (const float*)d_in[0];
    // d_in[1] = attention_mask: recomputed analytically, not read
    const float* Wq = (const float*)d_in[2];
    const float* Wk = (const float*)d_in[3];
    const float* Wv = (const float*)d_in[4];
    const float* Wo = (const float*)d_in[5];
    const int* pos = (const int*)d_in[6];
    float* out = (float*)d_out;

    // workspace layout (85 MiB total, aggressive aliasing):
    //  [0,18M)   Hb  [S][2304] bf16            -> dead after QKV GEMM; Qb [S][2048] (16M) aliases
    //  [18,37M)  Wqkv [4096][2304] bf16 (19M)  -> dead after QKV GEMM; Wo bf16 (9M) aliases
    //  [37,69M)  QKVf [S][4096] bf16 (32M)     -> dead after rope+transpose; Oa (16M) aliases
    //  [69,77M)  Kb  [S][1024] bf16 (8M)
    //  [77,85M)  Vt  [1024][S] bf16 (8M)
    char* ws = (char*)d_ws;
    unsigned short* Hb   = (unsigned short*)(ws);
    unsigned short* Qb   = (unsigned short*)(ws);
    unsigned short* Wqkv = (unsigned short*)(ws + (size_t)(18 << 20));
    unsigned short* QKVf = (unsigned short*)(ws + (size_t)(37 << 20));
    unsigned short* Oa   = (unsigned short*)(ws + (size_t)(37 << 20));
    unsigned short* Kb   = (unsigned short*)(ws + (size_t)(69 << 20));
    unsigned short* Vt   = (unsigned short*)(ws + (size_t)(77 << 20));

    cvt_bf16<<<(S * HID) / 1024, 256, 0, stream>>>(hidden, Hb);
    cvt_bf16<<<(QDIM * HID) / 1024, 256, 0, stream>>>(Wq, Wqkv);
    cvt_bf16<<<(KVDIM * HID) / 1024, 256, 0, stream>>>(Wk, Wqkv + (size_t)QDIM * HID);
    cvt_bf16<<<(KVDIM * HID) / 1024, 256, 0, stream>>>(Wv, Wqkv + (size_t)(QDIM + KVDIM) * HID);

    // fused QKV projection on the 256^2 8-phase kernel: grid 16x16 = 256 blocks
    bf16_gemm_8ph<<<256, 512, 0, stream>>>(Hb, Wqkv, QKVf, S, QKVDIM, HID);

    rope_kernel<<<(S * 12 * 128) / 256, 256, 0, stream>>>(QKVf, Qb, Kb, pos);
    transpose_v<<<dim3(S / 64, KVDIM / 64), 256, 0, stream>>>(QKVf, Vt);

    attn_kernel<<<512, 256, 0, stream>>>(Qb, Kb, Vt, Oa);

    cvt_bf16<<<(HID * QDIM) / 1024, 256, 0, stream>>>(Wo, Wqkv);
    bf16_gemm_bt<float><<<dim3(HID / 128, S / 128), 256, 0, stream>>>(Oa, Wqkv, out, S, HID, QDIM);
}